// Round 2
// baseline (520.291 us; speedup 1.0000x reference)
//
#include <hip/hip_runtime.h>
#include <cstdint>
#include <cstddef>

// Problem constants (B=4, S=2048, D=1024)
#define DD 1024
#define SSEQ 2048
#define NB 4
#define MROWS 8192          // B*S
#define FBINS 513           // rfft bins for N=1024
#define FPAD 520            // padded row stride for Scum buffer
#define WFP 1152            // per-projection padded fp32 column count (9 tiles)
#define NQKV 3456           // 3 * WFP = 27 tiles of 128
#define NHID 4096
#define NCHUNK 64           // scan chunks over S
#define SCHUNK 32           // S per chunk

typedef _Float16 f16_t;
typedef _Float16 f16x8 __attribute__((ext_vector_type(8)));
typedef _Float16 f16x2 __attribute__((ext_vector_type(2)));
typedef float f32x4 __attribute__((ext_vector_type(4)));

__device__ __forceinline__ float2 cmul(float2 a, float2 b) {
  return make_float2(a.x * b.x - a.y * b.y, a.x * b.y + a.y * b.x);
}

// Async global->LDS 16B copy (m97: width=16 emits global_load_lds_dwordx4).
__device__ __forceinline__ void async_cp16(const void* g, void* l) {
  __builtin_amdgcn_global_load_lds(
      (const __attribute__((address_space(1))) void*)g,
      (__attribute__((address_space(3))) void*)l, 16, 0, 0);
}

// Counted vmcnt waits (T4): literal immediates via specialization.
template <int N> __device__ __forceinline__ void vwait();
template <> __device__ __forceinline__ void vwait<0>() { asm volatile("s_waitcnt vmcnt(0)" ::: "memory"); }
template <> __device__ __forceinline__ void vwait<1>() { asm volatile("s_waitcnt vmcnt(1)" ::: "memory"); }
template <> __device__ __forceinline__ void vwait<2>() { asm volatile("s_waitcnt vmcnt(2)" ::: "memory"); }
template <> __device__ __forceinline__ void vwait<3>() { asm volatile("s_waitcnt vmcnt(3)" ::: "memory"); }
template <> __device__ __forceinline__ void vwait<4>() { asm volatile("s_waitcnt vmcnt(4)" ::: "memory"); }

// Branchless erf-based gelu, A&S 7.1.26 (|eps_erf| <= 1.5e-7).
__device__ __forceinline__ float fast_gelu(float val) {
  float av = __builtin_fabsf(val);
  float z = av * 0.70710678118654752f;
  float t = __builtin_amdgcn_rcpf(__builtin_fmaf(0.3275911f, z, 1.0f));
  float poly = t * __builtin_fmaf(t,
      __builtin_fmaf(t, __builtin_fmaf(t,
          __builtin_fmaf(t, 1.061405429f, -1.453152027f),
          1.421413741f), -0.284496736f), 0.254829592f);
  float e = __builtin_amdgcn_exp2f(z * z * -1.4426950408889634f);
  float w = poly * e;
  float r = fmaxf(val, 0.0f);
  return __builtin_fmaf(-0.5f * av, w, r);
}

// 1024-pt complex FFT over LDS ping-pong buffers; result lands back in bufA.
__device__ __forceinline__ void fft1024(float2* bufA, float2* bufB,
                                        const float2* tw, int tid) {
  float2* s = bufA;
  float2* d = bufB;
  for (int m = 1; m < 1024; m <<= 1) {
#pragma unroll
    for (int r2 = 0; r2 < 2; ++r2) {
      int u = tid + r2 * 256;
      int k = u & (m - 1);
      int jm = u - k;
      float2 c0 = s[u];
      float2 c1 = s[u + 512];
      float2 wt = tw[jm];
      float2 su = make_float2(c0.x + c1.x, c0.y + c1.y);
      float2 df = make_float2(c0.x - c1.x, c0.y - c1.y);
      float2 pr = cmul(wt, df);
      d[2 * jm + k] = su;
      d[2 * jm + k + m] = pr;
    }
    __syncthreads();
    float2* tmp = s; s = d; d = tmp;
  }
}

// 512-pt complex FFT (one butterfly per thread per stage); returns result ptr.
__device__ __forceinline__ float2* fft512(float2* bufA, float2* bufB,
                                          const float2* tw, int tid) {
  float2* s = bufA;
  float2* d = bufB;
  for (int m = 1; m < 512; m <<= 1) {
    int u = tid;
    int k = u & (m - 1);
    int jm = u - k;
    float2 c0 = s[u];
    float2 c1 = s[u + 256];
    float2 wt = tw[jm];
    float2 su = make_float2(c0.x + c1.x, c0.y + c1.y);
    float2 df = make_float2(c0.x - c1.x, c0.y - c1.y);
    float2 pr = cmul(wt, df);
    d[2 * jm + k] = su;
    d[2 * jm + k + m] = pr;
    __syncthreads();
    float2* tmp = s; s = d; d = tmp;
  }
  return s;   // 9 stages -> result in bufB
}

// ---------------------------------------------------------------------------
// Weight-row FFT: WfAll[p][k][j] = interleaved Re/Im of rfft(W_p[k, :]).
// ---------------------------------------------------------------------------
__global__ __launch_bounds__(256) void wfft_k(
    const float* __restrict__ Wq, const float* __restrict__ Wk,
    const float* __restrict__ Wv, float* __restrict__ WfAll) {
  __shared__ float2 tw[512];
  __shared__ float2 bufA[1024];
  __shared__ float2 bufB[1024];
  const int tid = threadIdx.x;
  const int p = blockIdx.x >> 10, k = blockIdx.x & 1023;
  const float* W = (p == 0) ? Wq : ((p == 1) ? Wk : Wv);
  for (int t = tid; t < 512; t += 256) {
    float ang = -6.2831853071795864769f * (float)t * (1.0f / 1024.0f);
    tw[t] = make_float2(cosf(ang), sinf(ang));
  }
  const float* src = W + (size_t)k * DD;
  for (int t = tid; t < 1024; t += 256) bufA[t] = make_float2(src[t], 0.f);
  __syncthreads();
  fft1024(bufA, bufB, tw, tid);
  float* dst = WfAll + ((size_t)p * DD + k) * WFP;
  for (int t = tid; t <= 512; t += 256) {
    float2 f = bufA[t];
    dst[2 * t] = f.x;
    dst[2 * t + 1] = f.y;
  }
  for (int j = 1026 + tid; j < WFP; j += 256) dst[j] = 0.f;
}

// ---------------------------------------------------------------------------
// Bias FFT (blocks 0..2).
// ---------------------------------------------------------------------------
__global__ __launch_bounds__(256) void bfft_k(
    const float* __restrict__ bq, const float* __restrict__ bk,
    const float* __restrict__ bv, float* __restrict__ biasC) {
  __shared__ float2 tw[512];
  __shared__ float2 bufA[1024];
  __shared__ float2 bufB[1024];
  const int tid = threadIdx.x;
  const int p = blockIdx.x;
  const float* bsrc = (p == 0) ? bq : ((p == 1) ? bk : bv);
  for (int t = tid; t < 512; t += 256) {
    float ang = -6.2831853071795864769f * (float)t * (1.0f / 1024.0f);
    tw[t] = make_float2(cosf(ang), sinf(ang));
  }
  for (int t = tid; t < 1024; t += 256) bufA[t] = make_float2(bsrc[t], 0.f);
  __syncthreads();
  fft1024(bufA, bufB, tw, tid);
  float* dst = biasC + (size_t)p * WFP;
  for (int t = tid; t <= 512; t += 256) {
    float2 f = bufA[t];
    dst[2 * t] = f.x;
    dst[2 * t + 1] = f.y;
  }
  for (int j = 1026 + tid; j < WFP; j += 256) dst[j] = 0.f;
}

// ---------------------------------------------------------------------------
// Transpose + cast fp32 (K x N) -> fp16 (N x K)
// ---------------------------------------------------------------------------
__global__ __launch_bounds__(256) void transpose_cast_k(
    const float* __restrict__ W, f16_t* __restrict__ Wt, int K, int N) {
  __shared__ float tile[32][33];
  const int tx = threadIdx.x & 31, ty = threadIdx.x >> 5;  // 32 x 8
  const int n0 = blockIdx.x * 32, k0 = blockIdx.y * 32;
#pragma unroll
  for (int i = 0; i < 32; i += 8)
    tile[ty + i][tx] = W[(size_t)(k0 + ty + i) * N + n0 + tx];
  __syncthreads();
#pragma unroll
  for (int i = 0; i < 32; i += 8)
    Wt[(size_t)(n0 + ty + i) * K + k0 + tx] = (f16_t)tile[tx][ty + i];
}

// ---------------------------------------------------------------------------
// LayerNorm (fp32 in) -> split fp16 hi/lo.  One block per row of 1024.
// ---------------------------------------------------------------------------
__global__ __launch_bounds__(256) void ln_cast2_k(
    const float* __restrict__ x, const float* __restrict__ g,
    const float* __restrict__ b, f16_t* __restrict__ hH,
    f16_t* __restrict__ hL) {
  const int row = blockIdx.x, tid = threadIdx.x;
  __shared__ float red[8];
  const float* xr = x + (size_t)row * DD;
  float v[4], ls = 0.f, lq = 0.f;
#pragma unroll
  for (int i = 0; i < 4; ++i) {
    v[i] = xr[i * 256 + tid];
    ls += v[i];
    lq += v[i] * v[i];
  }
#pragma unroll
  for (int o = 32; o > 0; o >>= 1) {
    ls += __shfl_down(ls, o);
    lq += __shfl_down(lq, o);
  }
  const int lane = tid & 63, w = tid >> 6;
  if (lane == 0) { red[w] = ls; red[w + 4] = lq; }
  __syncthreads();
  const float S = red[0] + red[1] + red[2] + red[3];
  const float Q = red[4] + red[5] + red[6] + red[7];
  const float mean = S * (1.f / 1024.f);
  const float var = Q * (1.f / 1024.f) - mean * mean;
  const float rs = rsqrtf(var + 1e-5f);
#pragma unroll
  for (int i = 0; i < 4; ++i) {
    int n = i * 256 + tid;
    float val = (v[i] - mean) * rs * g[n] + b[n];
    f16_t hi = (f16_t)val;
    hH[(size_t)row * DD + n] = hi;
    hL[(size_t)row * DD + n] = (f16_t)(val - (float)hi);
  }
}

// ---------------------------------------------------------------------------
// 8-phase GEMM building blocks (strip-interleaved wave decomposition).
//   stage order (tile t+1, issued in phases 1..4 of tile t): A0,B0,B1,A1
//   need  order (tile t):  ph1{A0,B0}  ph2{B1}  ph3{A1}  ph4{}
//   steady waits: ph1 vmcnt(2*LA), ph2 vmcnt(LA+LB), ph3 none, ph4 vmcnt(LA+LB)
// ---------------------------------------------------------------------------
template <int RHALF>
__device__ __forceinline__ void stage_half(const f16_t* __restrict__ G,
                                           int grow0, int ldk, int kt,
                                           f16_t* ls, int w, int lane) {
  const int srow = lane >> 3;
  const int slot = lane & 7;
#pragma unroll
  for (int j = 0; j < RHALF / 64; ++j) {
    const int rb = (w + j * 8) * 8;           // row block within half
    const int row = rb + srow;
    const int gg = (slot - (row & 7)) & 7;    // pre-swizzled global col-group
    async_cp16(G + (size_t)(grow0 + row) * ldk + kt + gg * 8, ls + rb * 64);
  }
}

template <int BM, int BN>
__device__ __forceinline__ void readA(const f16_t* As, int mq, int wm, int lane,
                                      f16x8 (&aR)[BM / 64][2]) {
#pragma unroll
  for (int mf = 0; mf < BM / 64; ++mf) {
    const int m = mq * (BM / 2) + wm * (BM / 4) + mf * 16 + (lane & 15);
#pragma unroll
    for (int ks = 0; ks < 2; ++ks) {
      const int cg = ks * 4 + (lane >> 4);
      const int sl = (cg + (m & 7)) & 7;
      aR[mf][ks] = *(const f16x8*)(As + m * 64 + sl * 8);
    }
  }
}

template <int BM, int BN>
__device__ __forceinline__ void readB(const f16_t* Bs, int nq, int wn, int lane,
                                      f16x8 (&bR)[BN / 128][2]) {
#pragma unroll
  for (int nf = 0; nf < BN / 128; ++nf) {
    const int n = nq * (BN / 2) + wn * (BN / 8) + nf * 16 + (lane & 15);
#pragma unroll
    for (int ks = 0; ks < 2; ++ks) {
      const int cg = ks * 4 + (lane >> 4);
      const int sl = (cg + (n & 7)) & 7;
      bR[nf][ks] = *(const f16x8*)(Bs + n * 64 + sl * 8);
    }
  }
}

template <int MF, int NF>
__device__ __forceinline__ void mfma_q(f32x4 (&acc)[MF][NF],
                                       const f16x8 (&aR)[MF][2],
                                       const f16x8 (&bR)[NF][2]) {
#pragma unroll
  for (int ks = 0; ks < 2; ++ks)
#pragma unroll
    for (int mf = 0; mf < MF; ++mf)
#pragma unroll
      for (int nf = 0; nf < NF; ++nf)
        acc[mf][nf] = __builtin_amdgcn_mfma_f32_16x16x32_f16(
            aR[mf][ks], bR[nf][ks], acc[mf][nf], 0, 0, 0);
}

// EPI 1: fast-gelu -> fp16.  EPI 2: +bias+resid -> fp32.
template <int BM, int BN, int MM, int NN, int KK, int EPI>
__global__ __launch_bounds__(512, 2) void gemm8p_k(
    const f16_t* __restrict__ A, const f16_t* __restrict__ Bt,
    const float* __restrict__ bias, const float* __restrict__ resid,
    float* __restrict__ outF, f16_t* __restrict__ outH) {
  constexpr int MF = BM / 64;      // M-frags per phase (one strip)
  constexpr int NF = BN / 128;     // N-frags per phase
  constexpr int LA = BM / 128;     // loads/thread per A-half
  constexpr int LB = BN / 128;     // loads/thread per B-half
  constexpr int NT = KK / 64;
  constexpr int TILE = (BM + BN) * 64;
  __shared__ alignas(16) f16_t lds[2 * TILE];

  const int tid = threadIdx.x;
  const int lane = tid & 63;
  const int w = tid >> 6;          // 8 waves
  const int wm = w >> 2;           // 0..1
  const int wn = w & 3;            // 0..3

  constexpr int ntm = MM / BM, ntn = NN / BN;
  constexpr int per = (ntm * ntn) / 8;   // nwg % 8 == 0 for both instantiations
  const int lin = (int)blockIdx.x;
  const int s = (lin & 7) * per + (lin >> 3);
  const int bn = (s % ntn) * BN;
  const int bm = (s / ntn) * BM;

  f32x4 acc[2][2][MF][NF];
#pragma unroll
  for (int a0 = 0; a0 < 2; ++a0)
#pragma unroll
    for (int a1 = 0; a1 < 2; ++a1)
#pragma unroll
      for (int mf = 0; mf < MF; ++mf)
#pragma unroll
        for (int nf = 0; nf < NF; ++nf)
          acc[a0][a1][mf][nf] = (f32x4){0.f, 0.f, 0.f, 0.f};

  // prologue: stage tile 0 in need-order A0,B0,B1,A1; wait for A0,B0.
  {
    f16_t* A0s = lds;
    f16_t* B0s = lds + BM * 64;
    stage_half<BM / 2>(A, bm, KK, 0, A0s, w, lane);
    stage_half<BN / 2>(Bt, bn, KK, 0, B0s, w, lane);
    stage_half<BN / 2>(Bt, bn + BN / 2, KK, 0, B0s + (BN / 2) * 64, w, lane);
    stage_half<BM / 2>(A, bm + BM / 2, KK, 0, A0s + (BM / 2) * 64, w, lane);
  }
  vwait<LA + LB>();
  __builtin_amdgcn_s_barrier();

  f16x8 aR[MF][2], bR0[NF][2], bR1[NF][2];

  for (int t = 0; t < NT; ++t) {
    const int cur = t & 1;
    f16_t* As = lds + cur * TILE;
    f16_t* Bs = As + BM * 64;
    f16_t* Asn = lds + (cur ^ 1) * TILE;
    f16_t* Bsn = Asn + BM * 64;
    const bool pre = (t + 1 < NT);
    const int ktn = (t + 1) << 6;

    // ---- phase 1: Q(0,0) --------------------------------------------------
    readA<BM, BN>(As, 0, wm, lane, aR);
    readB<BM, BN>(Bs, 0, wn, lane, bR0);
    if (pre) stage_half<BM / 2>(A, bm, KK, ktn, Asn, w, lane);
    __builtin_amdgcn_s_barrier();
    __builtin_amdgcn_s_setprio(1);
    mfma_q<MF, NF>(acc[0][0], aR, bR0);
    __builtin_amdgcn_s_setprio(0);
    if (pre) vwait<2 * LA>(); else vwait<LA>();
    __builtin_amdgcn_s_barrier();

    // ---- phase 2: Q(0,1) --------------------------------------------------
    readB<BM, BN>(Bs, 1, wn, lane, bR1);
    if (pre) stage_half<BN / 2>(Bt, bn, KK, ktn, Bsn, w, lane);
    __builtin_amdgcn_s_barrier();
    __builtin_amdgcn_s_setprio(1);
    mfma_q<MF, NF>(acc[0][1], aR, bR1);
    __builtin_amdgcn_s_setprio(0);
    if (pre) vwait<LA + LB>(); else vwait<0>();
    __builtin_amdgcn_s_barrier();

    // ---- phase 3: Q(1,0) --------------------------------------------------
    readA<BM, BN>(As, 1, wm, lane, aR);
    if (pre) stage_half<BN / 2>(Bt, bn + BN / 2, KK, ktn,
                                Bsn + (BN / 2) * 64, w, lane);
    __builtin_amdgcn_s_barrier();
    __builtin_amdgcn_s_setprio(1);
    mfma_q<MF, NF>(acc[1][0], aR, bR0);
    __builtin_amdgcn_s_setprio(0);
    __builtin_amdgcn_s_barrier();              // no vmcnt (ph4 reads nothing)

    // ---- phase 4: Q(1,1) --------------------------------------------------
    if (pre) stage_half<BM / 2>(A, bm + BM / 2, KK, ktn,
                                Asn + (BM / 2) * 64, w, lane);
    __builtin_amdgcn_s_barrier();
    __builtin_amdgcn_s_setprio(1);
    mfma_q<MF, NF>(acc[1][1], aR, bR1);
    __builtin_amdgcn_s_setprio(0);
    if (pre) vwait<LA + LB>();                 // boundary: A0',B0' landed
    __builtin_amdgcn_s_barrier();
  }

  const int q4 = lane >> 4;
  const int cn = lane & 15;
#pragma unroll
  for (int mq = 0; mq < 2; ++mq)
#pragma unroll
    for (int nq = 0; nq < 2; ++nq)
#pragma unroll
      for (int mf = 0; mf < MF; ++mf)
#pragma unroll
        for (int nf = 0; nf < NF; ++nf) {
          const int gcol = bn + nq * (BN / 2) + wn * (BN / 8) + nf * 16 + cn;
          const float bv = bias[gcol];
          const int grow0 = bm + mq * (BM / 2) + wm * (BM / 4) + mf * 16 + q4 * 4;
#pragma unroll
          for (int i = 0; i < 4; ++i) {
            const float val = acc[mq][nq][mf][nf][i] + bv;
            const size_t idx = (size_t)(grow0 + i) * NN + gcol;
            if (EPI == 1) {
              outH[idx] = (f16_t)fast_gelu(val);
            } else {
              outF[idx] = val + resid[idx];
            }
          }
        }
}

// ---------------------------------------------------------------------------
// QKV GEMM, 8-phase: M=8192, N=3456 (27x128), K folded for q precision.
// q-tiles (bn<1152): out = [Ahi|Alo] @ [Bq;Bq]  -> NT=32, A base switches at
// t=16, B column-group repeats (kt & 1023).  k/v-tiles: Ahi @ B, NT=16.
// BM=256, BN=128, 96 KiB LDS dbuf, 864 blocks (8 XCD chunks of 108; first 36
// of each chunk are heavy q-blocks so the first resident 256 are all heavy).
// Output: row stride NQKV, +bias epilogue.
// ---------------------------------------------------------------------------
__global__ __launch_bounds__(512, 2) void gemm_qkv8p_k(
    const f16_t* __restrict__ Ahi, const f16_t* __restrict__ Alo,
    const f16_t* __restrict__ Bt, const float* __restrict__ bias,
    float* __restrict__ outF) {
  constexpr int BM = 256, BN = 128;
  constexpr int MF = 4, NF = 1;      // BM/64, BN/128
  constexpr int LA = 2, LB = 1;      // loads/thread per half
  constexpr int TILE = (BM + BN) * 64;
  __shared__ alignas(16) f16_t lds[2 * TILE];

  const int tid = threadIdx.x;
  const int lane = tid & 63;
  const int w = tid >> 6;
  const int wm = w >> 2, wn = w & 3;

  // block mapping: chunk of 108 per XCD, heavy-first within chunk
  const int lin = (int)blockIdx.x;
  const int xcd = lin & 7, idx = lin >> 3;   // idx 0..107
  int bm, bn;
  bool qmode;
  if (idx < 36) {
    const int h = xcd * 36 + idx;            // 0..287
    bm = (h / 9) * 256;
    bn = (h % 9) * 128;
    qmode = true;
  } else {
    const int l = xcd * 72 + (idx - 36);     // 0..575
    bm = (l / 18) * 256;
    bn = 1152 + (l % 18) * 128;
    qmode = false;
  }
  const int NT = qmode ? 32 : 16;

  f32x4 acc[2][2][MF][NF];
#pragma unroll
  for (int a0 = 0; a0 < 2; ++a0)
#pragma unroll
    for (int a1 = 0; a1 < 2; ++a1)
#pragma unroll
      for (int mf = 0; mf < MF; ++mf)
#pragma unroll
        for (int nf = 0; nf < NF; ++nf)
          acc[a0][a1][mf][nf] = (f32x4){0.f, 0.f, 0.f, 0.f};

  // prologue: tile 0 (always hi, kt=0), need-order A0,B0,B1,A1
  {
    f16_t* A0s = lds;
    f16_t* B0s = lds + BM * 64;
    stage_half<BM / 2>(Ahi, bm, DD, 0, A0s, w, lane);
    stage_half<BN / 2>(Bt, bn, DD, 0, B0s, w, lane);
    stage_half<BN / 2>(Bt, bn + BN / 2, DD, 0, B0s + (BN / 2) * 64, w, lane);
    stage_half<BM / 2>(Ahi, bm + BM / 2, DD, 0, A0s + (BM / 2) * 64, w, lane);
  }
  vwait<LA + LB>();
  __builtin_amdgcn_s_barrier();

  f16x8 aR[MF][2], bR0[NF][2], bR1[NF][2];

  for (int t = 0; t < NT; ++t) {
    const int cur = t & 1;
    f16_t* As = lds + cur * TILE;
    f16_t* Bs = As + BM * 64;
    f16_t* Asn = lds + (cur ^ 1) * TILE;
    f16_t* Bsn = Asn + BM * 64;
    const bool pre = (t + 1 < NT);
    const int tt = t + 1;
    const f16_t* An = (qmode && tt >= 16) ? Alo : Ahi;   // K-fold base
    const int ktn = (tt & 15) << 6;                      // B repeats for lo

    // ---- phase 1: Q(0,0) --------------------------------------------------
    readA<BM, BN>(As, 0, wm, lane, aR);
    readB<BM, BN>(Bs, 0, wn, lane, bR0);
    if (pre) stage_half<BM / 2>(An, bm, DD, ktn, Asn, w, lane);
    __builtin_amdgcn_s_barrier();
    __builtin_amdgcn_s_setprio(1);
    mfma_q<MF, NF>(acc[0][0], aR, bR0);
    __builtin_amdgcn_s_setprio(0);
    if (pre) vwait<2 * LA>(); else vwait<LA>();
    __builtin_amdgcn_s_barrier();

    // ---- phase 2: Q(0,1) --------------------------------------------------
    readB<BM, BN>(Bs, 1, wn, lane, bR1);
    if (pre) stage_half<BN / 2>(Bt, bn, DD, ktn, Bsn, w, lane);
    __builtin_amdgcn_s_barrier();
    __builtin_amdgcn_s_setprio(1);
    mfma_q<MF, NF>(acc[0][1], aR, bR1);
    __builtin_amdgcn_s_setprio(0);
    if (pre) vwait<LA + LB>(); else vwait<0>();
    __builtin_amdgcn_s_barrier();

    // ---- phase 3: Q(1,0) --------------------------------------------------
    readA<BM, BN>(As, 1, wm, lane, aR);
    if (pre) stage_half<BN / 2>(Bt, bn + BN / 2, DD, ktn,
                                Bsn + (BN / 2) * 64, w, lane);
    __builtin_amdgcn_s_barrier();
    __builtin_amdgcn_s_setprio(1);
    mfma_q<MF, NF>(acc[1][0], aR, bR0);
    __builtin_amdgcn_s_setprio(0);
    __builtin_amdgcn_s_barrier();

    // ---- phase 4: Q(1,1) --------------------------------------------------
    if (pre) stage_half<BM / 2>(An, bm + BM / 2, DD, ktn,
                                Asn + (BM / 2) * 64, w, lane);
    __builtin_amdgcn_s_barrier();
    __builtin_amdgcn_s_setprio(1);
    mfma_q<MF, NF>(acc[1][1], aR, bR1);
    __builtin_amdgcn_s_setprio(0);
    if (pre) vwait<LA + LB>();
    __builtin_amdgcn_s_barrier();
  }

  const int q4 = lane >> 4;
  const int cn = lane & 15;
#pragma unroll
  for (int mq = 0; mq < 2; ++mq)
#pragma unroll
    for (int nq = 0; nq < 2; ++nq)
#pragma unroll
      for (int mf = 0; mf < MF; ++mf)
#pragma unroll
        for (int nf = 0; nf < NF; ++nf) {
          const int gcol = bn + nq * (BN / 2) + wn * (BN / 8) + nf * 16 + cn;
          const float bv = bias[gcol];
          const int grow0 = bm + mq * (BM / 2) + wm * (BM / 4) + mf * 16 + q4 * 4;
#pragma unroll
          for (int i = 0; i < 4; ++i) {
            const size_t oidx = (size_t)(grow0 + i) * NQKV + gcol;
            outF[oidx] = acc[mq][nq][mf][nf][i] + bv;
          }
        }
}

// ---------------------------------------------------------------------------
// Inline normalize helpers reading raw bins from qkv_f rows (1728 float2).
// ---------------------------------------------------------------------------
__device__ __forceinline__ float2 unitc(float2 a) {
  float inv = 1.0f / fmaxf(sqrtf(a.x * a.x + a.y * a.y), 1e-8f);
  return make_float2(a.x * inv, a.y * inv);
}
__device__ __forceinline__ float2 bind_bin(const float2* r, int f) {
  float2 kn = unitc(r[576 + f]);
  float2 vn = unitc(r[1152 + f]);
  return cmul(kn, vn);
}

// ---------------------------------------------------------------------------
// 3-pass parallel prefix sum over S per (batch, bin), P computed inline.
// ---------------------------------------------------------------------------
__global__ __launch_bounds__(256) void scan_pass1_k(
    const float* __restrict__ qkvF, float2* __restrict__ T) {
  const int bid = blockIdx.x;
  const int sc = bid & 63;
  const int fh = (bid >> 6) & 1;
  const int b = bid >> 7;
  const int s0 = sc * SCHUNK;
  const float2* base = (const float2*)(qkvF + ((size_t)(b * SSEQ + s0)) * NQKV);
  for (int f = fh * 256 + threadIdx.x; f < FBINS; f += 512) {
    float2 acc = make_float2(0.f, 0.f);
    const float2* r = base;
    for (int i = 0; i < SCHUNK; ++i) {
      float2 pv = bind_bin(r, f);
      acc.x += pv.x; acc.y += pv.y;
      r += NQKV / 2;
    }
    T[((size_t)b * NCHUNK + sc) * FBINS + f] = acc;
  }
}

__global__ void scan_pass2_k(float2* __restrict__ T) {
  const int idx = blockIdx.x * 256 + threadIdx.x;
  if (idx >= NB * FBINS) return;
  const int b = idx / FBINS, f = idx % FBINS;
  float2 acc = make_float2(0.f, 0.f);
  for (int sc = 0; sc < NCHUNK; ++sc) {
    size_t a = ((size_t)b * NCHUNK + sc) * FBINS + f;
    float2 v = T[a];
    T[a] = acc;
    acc.x += v.x; acc.y += v.y;
  }
}

__global__ __launch_bounds__(256) void scan_pass3_k(
    const float* __restrict__ qkvF, const float2* __restrict__ T,
    float2* __restrict__ Scum) {
  const int bid = blockIdx.x;
  const int sc = bid & 63;
  const int fh = (bid >> 6) & 1;
  const int b = bid >> 7;
  const int s0 = sc * SCHUNK;
  const float2* base = (const float2*)(qkvF + ((size_t)(b * SSEQ + s0)) * NQKV);
  for (int f = fh * 256 + threadIdx.x; f < FBINS; f += 512) {
    float2 acc = T[((size_t)b * NCHUNK + sc) * FBINS + f];
    const float2* r = base;
    size_t orow = ((size_t)(b * SSEQ + s0)) * FPAD + f;
    for (int i = 0; i < SCHUNK; ++i) {
      float2 pv = bind_bin(r, f);
      acc.x += pv.x; acc.y += pv.y;
      Scum[orow] = acc;
      r += NQKV / 2;
      orow += FPAD;
    }
  }
}

// ---------------------------------------------------------------------------
// Per-row: Fq = unit(q bins); M = Scum .* conj(Fq); mixed = irfft(M) via
// packed real inverse; x2 = x + mixed; h2 = LN2(x2) -> fp16.
// ---------------------------------------------------------------------------
__global__ __launch_bounds__(256) void unbind_ln2_k(
    const float2* __restrict__ Scum, const float* __restrict__ qkvF,
    const float* __restrict__ x, float* __restrict__ x2out,
    f16_t* __restrict__ h2, const float* __restrict__ g2,
    const float* __restrict__ b2) {
  __shared__ float2 tw[256];     // e^{+2pi i t/512}
  __shared__ float2 Marr[513];
  __shared__ float2 bufA[512];
  __shared__ float2 bufB[512];
  __shared__ float red[8];
  const int tid = threadIdx.x;
  const int row = blockIdx.x;

  {
    float ang = 6.2831853071795864769f * (float)tid * (1.0f / 512.0f);
    tw[tid] = make_float2(cosf(ang), sinf(ang));
  }
  const float2* qrow = (const float2*)(qkvF + (size_t)row * NQKV);
  for (int t = tid; t <= 512; t += 256) {
    float2 sc = Scum[(size_t)row * FPAD + t];
    float2 fq = unitc(qrow[t]);
    Marr[t] = make_float2(sc.x * fq.x + sc.y * fq.y, sc.y * fq.x - sc.x * fq.y);
  }
  __syncthreads();
#pragma unroll
  for (int rr = 0; rr < 2; ++rr) {
    int t = tid + rr * 256;
    float2 a = Marr[t];
    float2 b = Marr[512 - t];
    float2 E = make_float2(0.5f * (a.x + b.x), 0.5f * (a.y - b.y));
    float2 Dd = make_float2(0.5f * (a.x - b.x), 0.5f * (a.y + b.y));
    float ang = 6.2831853071795864769f * (float)t * (1.0f / 1024.0f);
    float cw = cosf(ang), sw = sinf(ang);
    float2 O = make_float2(cw * Dd.x - sw * Dd.y, cw * Dd.y + sw * Dd.x);
    bufA[t] = make_float2(E.x - O.y, E.y + O.x);
  }
  __syncthreads();
  float2* res = fft512(bufA, bufB, tw, tid);

  const float* xr = x + (size_t)row * DD;
  float v[2][2];
  float ls = 0.f, lq = 0.f;
#pragma unroll
  for (int rr = 0; rr < 2; ++rr) {
    int n = tid + rr * 256;
    float2 z = res[n];
    float2 xv = *(const float2*)(xr + 2 * n);
    float v0 = xv.x + z.x * (1.0f / 512.0f);
    float v1 = xv.y + z.y * (1.0f / 512.0f);
    *(float2*)(x2out + (size_t)row * DD + 2 * n) = make_float2(v0, v1);
    v[rr][0] = v0; v[rr][1] = v1;
    ls += v0 + v1;
    lq += v0 * v0 + v1 * v1;
  }
#pragma unroll
  for (int o = 32; o > 0; o >>= 1) {
    ls += __shfl_down(ls, o);
    lq += __shfl_down(lq, o);
  }
  const int lane = tid & 63, w = tid >> 6;
  if (lane == 0) { red[w] = ls; red[w + 4] = lq; }
  __syncthreads();
  const float S = red[0] + red[1] + red[2] + red[3];
  const float Q = red[4] + red[5] + red[6] + red[7];
  const float mean = S * (1.f / 1024.f);
  const float var = Q * (1.f / 1024.f) - mean * mean;
  const float rs = rsqrtf(var + 1e-5f);
  f16_t* hr = h2 + (size_t)row * DD;
#pragma unroll
  for (int rr = 0; rr < 2; ++rr) {
    int n = tid + rr * 256;
    float2 gv = *(const float2*)(g2 + 2 * n);
    float2 bv = *(const float2*)(b2 + 2 * n);
    f16x2 hp;
    hp[0] = (f16_t)((v[rr][0] - mean) * rs * gv.x + bv.x);
    hp[1] = (f16_t)((v[rr][1] - mean) * rs * gv.y + bv.y);
    *(f16x2*)(hr + 2 * n) = hp;
  }
}

// ---------------------------------------------------------------------------
extern "C" void kernel_launch(void* const* d_in, const int* in_sizes, int n_in,
                              void* d_out, int out_size, void* d_ws,
                              size_t ws_size, hipStream_t stream) {
  const float* x     = (const float*)d_in[0];
  const float* Wq    = (const float*)d_in[1];
  const float* bq    = (const float*)d_in[2];
  const float* Wk    = (const float*)d_in[3];
  const float* bk    = (const float*)d_in[4];
  const float* Wv    = (const float*)d_in[5];
  const float* bv    = (const float*)d_in[6];
  const float* ln1_g = (const float*)d_in[7];
  const float* ln1_b = (const float*)d_in[8];
  const float* ln2_g = (const float*)d_in[9];
  const float* ln2_b = (const float*)d_in[10];
  const float* W1    = (const float*)d_in[11];
  const float* b1    = (const float*)d_in[12];
  const float* W2    = (const float*)d_in[13];
  const float* b2    = (const float*)d_in[14];
  float* out = (float*)d_out;

  char* p = (char*)d_ws;
  auto take = [&](size_t bytes) {
    char* r = p;
    p += (bytes + 255) & ~(size_t)255;
    return r;
  };
  f16_t* BtH   = (f16_t*)take((size_t)NQKV * DD * sizeof(f16_t));
  f16_t* W1T   = (f16_t*)take((size_t)NHID * DD * sizeof(f16_t));
  f16_t* W2T   = (f16_t*)take((size_t)DD * NHID * sizeof(f16_t));
  float* biasC = (float*)take((size_t)NQKV * sizeof(float));
  f16_t* hbuf  = (f16_t*)take((size_t)MROWS * DD * sizeof(f16_t));   // h_hi, then h2
  char*  big   = take((size_t)MROWS * NQKV * sizeof(float));         // WfAll, qkvF, mlp1
  float2* Scum = (float2*)take((size_t)MROWS * FPAD * sizeof(float2));
  float* x2    = (float*)take((size_t)MROWS * DD * sizeof(float));
  float2* Tch  = (float2*)take((size_t)NB * NCHUNK * FBINS * sizeof(float2));
  // time-disjoint aliases:
  float* WfAll   = (float*)big;
  float* qkv_f   = (float*)big;
  f16_t* mlp1    = (f16_t*)big;
  f16_t* hlo     = (f16_t*)x2;

  // 1. FFT weight rows (fp32) -> WfAll[p][k][1152]
  wfft_k<<<3 * DD, 256, 0, stream>>>(Wq, Wk, Wv, WfAll);
  // 2. transpose + cast -> BtH (3456 x 1024)
  for (int pp = 0; pp < 3; ++pp)
    transpose_cast_k<<<dim3(WFP / 32, DD / 32), 256, 0, stream>>>(
        WfAll + (size_t)pp * DD * WFP,
        BtH + (size_t)pp * WFP * DD, DD, WFP);
  // 3. FFT biases -> biasC
  bfft_k<<<3, 256, 0, stream>>>(bq, bk, bv, biasC);
  // 4. MLP weights -> transposed fp16
  transpose_cast_k<<<dim3(128, 32), 256, 0, stream>>>(W1, W1T, DD, NHID);
  transpose_cast_k<<<dim3(32, 128), 256, 0, stream>>>(W2, W2T, NHID, DD);

  // 5. h = LN1(x) -> hi/lo fp16 pair
  ln_cast2_k<<<MROWS, 256, 0, stream>>>(x, ln1_g, ln1_b, hbuf, hlo);

  // 6. Fourier bins: qkv_f = h @ rfft_rows(W)^T + rfft(bias)  [8-phase]
  gemm_qkv8p_k<<<864, 512, 0, stream>>>(hbuf, hlo, BtH, biasC, qkv_f);

  // 7. causal prefix sum over S
  scan_pass1_k<<<NB * NCHUNK * 2, 256, 0, stream>>>(qkv_f, Tch);
  scan_pass2_k<<<(NB * FBINS + 255) / 256, 256, 0, stream>>>(Tch);
  scan_pass3_k<<<NB * NCHUNK * 2, 256, 0, stream>>>(qkv_f, Tch, Scum);

  // 8. unbind (packed real iFFT) + residual + LN2
  unbind_ln2_k<<<MROWS, 256, 0, stream>>>(Scum, qkv_f, x, x2, hbuf, ln2_g, ln2_b);

  // 9. mlp1 = gelu(h2 @ W1 + b1)   [8-phase 256x256, 512 blocks]
  gemm8p_k<256, 256, MROWS, NHID, DD, 1><<<512, 512, 0, stream>>>(
      hbuf, W1T, b1, nullptr, nullptr, mlp1);

  // 10. out = x2 + mlp1 @ W2 + b2  [8-phase 128x256, 256 blocks = 1/CU]
  gemm8p_k<128, 256, MROWS, DD, NHID, 2><<<256, 512, 0, stream>>>(
      mlp1, W2T, b2, x2, out, nullptr);
}

// Round 3
// 518.172 us; speedup vs baseline: 1.0041x; 1.0041x over previous
//
#include <hip/hip_runtime.h>
#include <cstdint>
#include <cstddef>

// Problem constants (B=4, S=2048, D=1024)
#define DD 1024
#define SSEQ 2048
#define NB 4
#define MROWS 8192          // B*S
#define FBINS 513           // rfft bins for N=1024
#define FPAD 520            // padded row stride for Scum buffer
#define WFP 1152            // per-projection padded fp32 column count (9 tiles)
#define NQKV 3456           // 3 * WFP = 27 tiles of 128
#define NHID 4096
#define NCHUNK 64           // scan chunks over S
#define SCHUNK 32           // S per chunk

typedef _Float16 f16_t;
typedef _Float16 f16x8 __attribute__((ext_vector_type(8)));
typedef _Float16 f16x2 __attribute__((ext_vector_type(2)));
typedef float f32x4 __attribute__((ext_vector_type(4)));

__device__ __forceinline__ float2 cmul(float2 a, float2 b) {
  return make_float2(a.x * b.x - a.y * b.y, a.x * b.y + a.y * b.x);
}

// Async global->LDS 16B copy (m97: width=16 emits global_load_lds_dwordx4).
__device__ __forceinline__ void async_cp16(const void* g, void* l) {
  __builtin_amdgcn_global_load_lds(
      (const __attribute__((address_space(1))) void*)g,
      (__attribute__((address_space(3))) void*)l, 16, 0, 0);
}

// Counted vmcnt waits (T4): literal immediates via specialization.
template <int N> __device__ __forceinline__ void vwait();
template <> __device__ __forceinline__ void vwait<0>() { asm volatile("s_waitcnt vmcnt(0)" ::: "memory"); }
template <> __device__ __forceinline__ void vwait<1>() { asm volatile("s_waitcnt vmcnt(1)" ::: "memory"); }
template <> __device__ __forceinline__ void vwait<2>() { asm volatile("s_waitcnt vmcnt(2)" ::: "memory"); }
template <> __device__ __forceinline__ void vwait<3>() { asm volatile("s_waitcnt vmcnt(3)" ::: "memory"); }
template <> __device__ __forceinline__ void vwait<4>() { asm volatile("s_waitcnt vmcnt(4)" ::: "memory"); }

// Branchless erf-based gelu, A&S 7.1.26 (|eps_erf| <= 1.5e-7).
__device__ __forceinline__ float fast_gelu(float val) {
  float av = __builtin_fabsf(val);
  float z = av * 0.70710678118654752f;
  float t = __builtin_amdgcn_rcpf(__builtin_fmaf(0.3275911f, z, 1.0f));
  float poly = t * __builtin_fmaf(t,
      __builtin_fmaf(t, __builtin_fmaf(t,
          __builtin_fmaf(t, 1.061405429f, -1.453152027f),
          1.421413741f), -0.284496736f), 0.254829592f);
  float e = __builtin_amdgcn_exp2f(z * z * -1.4426950408889634f);
  float w = poly * e;
  float r = fmaxf(val, 0.0f);
  return __builtin_fmaf(-0.5f * av, w, r);
}

// 1024-pt complex FFT over LDS ping-pong buffers; result lands back in bufA.
// lt in [0,256).  __syncthreads syncs the whole block (all rows in lockstep).
__device__ __forceinline__ void fft1024(float2* bufA, float2* bufB,
                                        const float2* tw, int lt) {
  float2* s = bufA;
  float2* d = bufB;
  for (int m = 1; m < 1024; m <<= 1) {
#pragma unroll
    for (int r2 = 0; r2 < 2; ++r2) {
      int u = lt + r2 * 256;
      int k = u & (m - 1);
      int jm = u - k;
      float2 c0 = s[u];
      float2 c1 = s[u + 512];
      float2 wt = tw[jm];
      float2 su = make_float2(c0.x + c1.x, c0.y + c1.y);
      float2 df = make_float2(c0.x - c1.x, c0.y - c1.y);
      float2 pr = cmul(wt, df);
      d[2 * jm + k] = su;
      d[2 * jm + k + m] = pr;
    }
    __syncthreads();
    float2* tmp = s; s = d; d = tmp;
  }
}

// 512-pt complex FFT (one butterfly per thread per stage); returns result ptr.
__device__ __forceinline__ float2* fft512(float2* bufA, float2* bufB,
                                          const float2* tw, int lt) {
  float2* s = bufA;
  float2* d = bufB;
  for (int m = 1; m < 512; m <<= 1) {
    int u = lt;
    int k = u & (m - 1);
    int jm = u - k;
    float2 c0 = s[u];
    float2 c1 = s[u + 256];
    float2 wt = tw[jm];
    float2 su = make_float2(c0.x + c1.x, c0.y + c1.y);
    float2 df = make_float2(c0.x - c1.x, c0.y - c1.y);
    float2 pr = cmul(wt, df);
    d[2 * jm + k] = su;
    d[2 * jm + k + m] = pr;
    __syncthreads();
    float2* tmp = s; s = d; d = tmp;
  }
  return s;   // 9 stages -> result in bufB
}

// ---------------------------------------------------------------------------
// Weight-row FFT, 2 rows per 512-thread block (halves per-row barrier cost).
// WfAll[p][k][j] = interleaved Re/Im of rfft(W_p[k, :]).
// ---------------------------------------------------------------------------
__global__ __launch_bounds__(512) void wfft_k(
    const float* __restrict__ Wq, const float* __restrict__ Wk,
    const float* __restrict__ Wv, float* __restrict__ WfAll) {
  __shared__ float2 tw[512];
  __shared__ float2 bufA[2][1024];
  __shared__ float2 bufB[2][1024];
  const int tid = threadIdx.x;
  const int rh = tid >> 8;          // row half 0/1
  const int lt = tid & 255;
  const int row = blockIdx.x * 2 + rh;
  const int p = row >> 10, k = row & 1023;
  const float* W = (p == 0) ? Wq : ((p == 1) ? Wk : Wv);
  if (rh == 0) {
    for (int t = lt; t < 512; t += 256) {
      float ang = -6.2831853071795864769f * (float)t * (1.0f / 1024.0f);
      tw[t] = make_float2(cosf(ang), sinf(ang));
    }
  }
  const float* src = W + (size_t)k * DD;
  for (int t = lt; t < 1024; t += 256) bufA[rh][t] = make_float2(src[t], 0.f);
  __syncthreads();
  fft1024(bufA[rh], bufB[rh], tw, lt);
  float* dst = WfAll + ((size_t)p * DD + k) * WFP;
  for (int t = lt; t <= 512; t += 256) {
    float2 f = bufA[rh][t];
    dst[2 * t] = f.x;
    dst[2 * t + 1] = f.y;
  }
  for (int j = 1026 + lt; j < WFP; j += 256) dst[j] = 0.f;
}

// ---------------------------------------------------------------------------
// Bias FFT (blocks 0..2).
// ---------------------------------------------------------------------------
__global__ __launch_bounds__(256) void bfft_k(
    const float* __restrict__ bq, const float* __restrict__ bk,
    const float* __restrict__ bv, float* __restrict__ biasC) {
  __shared__ float2 tw[512];
  __shared__ float2 bufA[1024];
  __shared__ float2 bufB[1024];
  const int tid = threadIdx.x;
  const int p = blockIdx.x;
  const float* bsrc = (p == 0) ? bq : ((p == 1) ? bk : bv);
  for (int t = tid; t < 512; t += 256) {
    float ang = -6.2831853071795864769f * (float)t * (1.0f / 1024.0f);
    tw[t] = make_float2(cosf(ang), sinf(ang));
  }
  for (int t = tid; t < 1024; t += 256) bufA[t] = make_float2(bsrc[t], 0.f);
  __syncthreads();
  fft1024(bufA, bufB, tw, tid);
  float* dst = biasC + (size_t)p * WFP;
  for (int t = tid; t <= 512; t += 256) {
    float2 f = bufA[t];
    dst[2 * t] = f.x;
    dst[2 * t + 1] = f.y;
  }
  for (int j = 1026 + tid; j < WFP; j += 256) dst[j] = 0.f;
}

// ---------------------------------------------------------------------------
// Transpose + cast fp32 (K x N) -> fp16 (N x K)
// ---------------------------------------------------------------------------
__global__ __launch_bounds__(256) void transpose_cast_k(
    const float* __restrict__ W, f16_t* __restrict__ Wt, int K, int N) {
  __shared__ float tile[32][33];
  const int tx = threadIdx.x & 31, ty = threadIdx.x >> 5;  // 32 x 8
  const int n0 = blockIdx.x * 32, k0 = blockIdx.y * 32;
#pragma unroll
  for (int i = 0; i < 32; i += 8)
    tile[ty + i][tx] = W[(size_t)(k0 + ty + i) * N + n0 + tx];
  __syncthreads();
#pragma unroll
  for (int i = 0; i < 32; i += 8)
    Wt[(size_t)(n0 + ty + i) * K + k0 + tx] = (f16_t)tile[tx][ty + i];
}

// ---------------------------------------------------------------------------
// LayerNorm (fp32 in) -> split fp16 hi/lo.  One block per row of 1024.
// ---------------------------------------------------------------------------
__global__ __launch_bounds__(256) void ln_cast2_k(
    const float* __restrict__ x, const float* __restrict__ g,
    const float* __restrict__ b, f16_t* __restrict__ hH,
    f16_t* __restrict__ hL) {
  const int row = blockIdx.x, tid = threadIdx.x;
  __shared__ float red[8];
  const float* xr = x + (size_t)row * DD;
  float v[4], ls = 0.f, lq = 0.f;
#pragma unroll
  for (int i = 0; i < 4; ++i) {
    v[i] = xr[i * 256 + tid];
    ls += v[i];
    lq += v[i] * v[i];
  }
#pragma unroll
  for (int o = 32; o > 0; o >>= 1) {
    ls += __shfl_down(ls, o);
    lq += __shfl_down(lq, o);
  }
  const int lane = tid & 63, w = tid >> 6;
  if (lane == 0) { red[w] = ls; red[w + 4] = lq; }
  __syncthreads();
  const float S = red[0] + red[1] + red[2] + red[3];
  const float Q = red[4] + red[5] + red[6] + red[7];
  const float mean = S * (1.f / 1024.f);
  const float var = Q * (1.f / 1024.f) - mean * mean;
  const float rs = rsqrtf(var + 1e-5f);
#pragma unroll
  for (int i = 0; i < 4; ++i) {
    int n = i * 256 + tid;
    float val = (v[i] - mean) * rs * g[n] + b[n];
    f16_t hi = (f16_t)val;
    hH[(size_t)row * DD + n] = hi;
    hL[(size_t)row * DD + n] = (f16_t)(val - (float)hi);
  }
}

// ---------------------------------------------------------------------------
// 8-phase GEMM building blocks (strip-interleaved wave decomposition).
// ---------------------------------------------------------------------------
template <int RHALF>
__device__ __forceinline__ void stage_half(const f16_t* __restrict__ G,
                                           int grow0, int ldk, int kt,
                                           f16_t* ls, int w, int lane) {
  const int srow = lane >> 3;
  const int slot = lane & 7;
#pragma unroll
  for (int j = 0; j < RHALF / 64; ++j) {
    const int rb = (w + j * 8) * 8;           // row block within half
    const int row = rb + srow;
    const int gg = (slot - (row & 7)) & 7;    // pre-swizzled global col-group
    async_cp16(G + (size_t)(grow0 + row) * ldk + kt + gg * 8, ls + rb * 64);
  }
}

template <int BM, int BN>
__device__ __forceinline__ void readA(const f16_t* As, int mq, int wm, int lane,
                                      f16x8 (&aR)[BM / 64][2]) {
#pragma unroll
  for (int mf = 0; mf < BM / 64; ++mf) {
    const int m = mq * (BM / 2) + wm * (BM / 4) + mf * 16 + (lane & 15);
#pragma unroll
    for (int ks = 0; ks < 2; ++ks) {
      const int cg = ks * 4 + (lane >> 4);
      const int sl = (cg + (m & 7)) & 7;
      aR[mf][ks] = *(const f16x8*)(As + m * 64 + sl * 8);
    }
  }
}

template <int BM, int BN>
__device__ __forceinline__ void readB(const f16_t* Bs, int nq, int wn, int lane,
                                      f16x8 (&bR)[BN / 128][2]) {
#pragma unroll
  for (int nf = 0; nf < BN / 128; ++nf) {
    const int n = nq * (BN / 2) + wn * (BN / 8) + nf * 16 + (lane & 15);
#pragma unroll
    for (int ks = 0; ks < 2; ++ks) {
      const int cg = ks * 4 + (lane >> 4);
      const int sl = (cg + (n & 7)) & 7;
      bR[nf][ks] = *(const f16x8*)(Bs + n * 64 + sl * 8);
    }
  }
}

template <int MF, int NF>
__device__ __forceinline__ void mfma_q(f32x4 (&acc)[MF][NF],
                                       const f16x8 (&aR)[MF][2],
                                       const f16x8 (&bR)[NF][2]) {
#pragma unroll
  for (int ks = 0; ks < 2; ++ks)
#pragma unroll
    for (int mf = 0; mf < MF; ++mf)
#pragma unroll
      for (int nf = 0; nf < NF; ++nf)
        acc[mf][nf] = __builtin_amdgcn_mfma_f32_16x16x32_f16(
            aR[mf][ks], bR[nf][ks], acc[mf][nf], 0, 0, 0);
}

// EPI 1: fast-gelu -> fp16.  EPI 2: +bias+resid -> fp32.
template <int BM, int BN, int MM, int NN, int KK, int EPI>
__global__ __launch_bounds__(512, 2) void gemm8p_k(
    const f16_t* __restrict__ A, const f16_t* __restrict__ Bt,
    const float* __restrict__ bias, const float* __restrict__ resid,
    float* __restrict__ outF, f16_t* __restrict__ outH) {
  constexpr int MF = BM / 64;      // M-frags per phase (one strip)
  constexpr int NF = BN / 128;     // N-frags per phase
  constexpr int LA = BM / 128;     // loads/thread per A-half
  constexpr int LB = BN / 128;     // loads/thread per B-half
  constexpr int NT = KK / 64;
  constexpr int TILE = (BM + BN) * 64;
  __shared__ alignas(16) f16_t lds[2 * TILE];

  const int tid = threadIdx.x;
  const int lane = tid & 63;
  const int w = tid >> 6;          // 8 waves
  const int wm = w >> 2;           // 0..1
  const int wn = w & 3;            // 0..3

  constexpr int ntm = MM / BM, ntn = NN / BN;
  constexpr int per = (ntm * ntn) / 8;   // nwg % 8 == 0 for both instantiations
  const int lin = (int)blockIdx.x;
  const int s = (lin & 7) * per + (lin >> 3);
  const int bn = (s % ntn) * BN;
  const int bm = (s / ntn) * BM;

  f32x4 acc[2][2][MF][NF];
#pragma unroll
  for (int a0 = 0; a0 < 2; ++a0)
#pragma unroll
    for (int a1 = 0; a1 < 2; ++a1)
#pragma unroll
      for (int mf = 0; mf < MF; ++mf)
#pragma unroll
        for (int nf = 0; nf < NF; ++nf)
          acc[a0][a1][mf][nf] = (f32x4){0.f, 0.f, 0.f, 0.f};

  // prologue: stage tile 0 in need-order A0,B0,B1,A1; wait for A0,B0.
  {
    f16_t* A0s = lds;
    f16_t* B0s = lds + BM * 64;
    stage_half<BM / 2>(A, bm, KK, 0, A0s, w, lane);
    stage_half<BN / 2>(Bt, bn, KK, 0, B0s, w, lane);
    stage_half<BN / 2>(Bt, bn + BN / 2, KK, 0, B0s + (BN / 2) * 64, w, lane);
    stage_half<BM / 2>(A, bm + BM / 2, KK, 0, A0s + (BM / 2) * 64, w, lane);
  }
  vwait<LA + LB>();
  __builtin_amdgcn_s_barrier();

  f16x8 aR[MF][2], bR0[NF][2], bR1[NF][2];

  for (int t = 0; t < NT; ++t) {
    const int cur = t & 1;
    f16_t* As = lds + cur * TILE;
    f16_t* Bs = As + BM * 64;
    f16_t* Asn = lds + (cur ^ 1) * TILE;
    f16_t* Bsn = Asn + BM * 64;
    const bool pre = (t + 1 < NT);
    const int ktn = (t + 1) << 6;

    // ---- phase 1: Q(0,0) --------------------------------------------------
    readA<BM, BN>(As, 0, wm, lane, aR);
    readB<BM, BN>(Bs, 0, wn, lane, bR0);
    if (pre) stage_half<BM / 2>(A, bm, KK, ktn, Asn, w, lane);
    __builtin_amdgcn_s_barrier();
    __builtin_amdgcn_s_setprio(1);
    mfma_q<MF, NF>(acc[0][0], aR, bR0);
    __builtin_amdgcn_s_setprio(0);
    if (pre) vwait<2 * LA>(); else vwait<LA>();
    __builtin_amdgcn_s_barrier();

    // ---- phase 2: Q(0,1) --------------------------------------------------
    readB<BM, BN>(Bs, 1, wn, lane, bR1);
    if (pre) stage_half<BN / 2>(Bt, bn, KK, ktn, Bsn, w, lane);
    __builtin_amdgcn_s_barrier();
    __builtin_amdgcn_s_setprio(1);
    mfma_q<MF, NF>(acc[0][1], aR, bR1);
    __builtin_amdgcn_s_setprio(0);
    if (pre) vwait<LA + LB>(); else vwait<0>();
    __builtin_amdgcn_s_barrier();

    // ---- phase 3: Q(1,0) --------------------------------------------------
    readA<BM, BN>(As, 1, wm, lane, aR);
    if (pre) stage_half<BN / 2>(Bt, bn + BN / 2, KK, ktn,
                                Bsn + (BN / 2) * 64, w, lane);
    __builtin_amdgcn_s_barrier();
    __builtin_amdgcn_s_setprio(1);
    mfma_q<MF, NF>(acc[1][0], aR, bR0);
    __builtin_amdgcn_s_setprio(0);
    __builtin_amdgcn_s_barrier();              // no vmcnt (ph4 reads nothing)

    // ---- phase 4: Q(1,1) --------------------------------------------------
    if (pre) stage_half<BM / 2>(A, bm + BM / 2, KK, ktn,
                                Asn + (BM / 2) * 64, w, lane);
    __builtin_amdgcn_s_barrier();
    __builtin_amdgcn_s_setprio(1);
    mfma_q<MF, NF>(acc[1][1], aR, bR1);
    __builtin_amdgcn_s_setprio(0);
    if (pre) vwait<LA + LB>();                 // boundary: A0',B0' landed
    __builtin_amdgcn_s_barrier();
  }

  const int q4 = lane >> 4;
  const int cn = lane & 15;
#pragma unroll
  for (int mq = 0; mq < 2; ++mq)
#pragma unroll
    for (int nq = 0; nq < 2; ++nq)
#pragma unroll
      for (int mf = 0; mf < MF; ++mf)
#pragma unroll
        for (int nf = 0; nf < NF; ++nf) {
          const int gcol = bn + nq * (BN / 2) + wn * (BN / 8) + nf * 16 + cn;
          const float bv = bias[gcol];
          const int grow0 = bm + mq * (BM / 2) + wm * (BM / 4) + mf * 16 + q4 * 4;
#pragma unroll
          for (int i = 0; i < 4; ++i) {
            const float val = acc[mq][nq][mf][nf][i] + bv;
            const size_t idx = (size_t)(grow0 + i) * NN + gcol;
            if (EPI == 1) {
              outH[idx] = (f16_t)fast_gelu(val);
            } else {
              outF[idx] = val + resid[idx];
            }
          }
        }
}

// ---------------------------------------------------------------------------
// QKV GEMM v2: 2 FAT phases per K-tile (16 MFMA/phase), BM=256 BN=128.
// Phase 1: acc[0][*] (top M-half x full N), reads aR(A0) + bR0,bR1 (B full,
//   held in regs across both phases).  Phase 2: acc[1][*] with aR(A1).
// Stage order per tile t (into other buffer, for tile t+1):
//   ph1 issues A0'(2 loads) + B'(2 loads); ph2 issues A1'(2 loads).
// FIFO waits: end-ph1 vmcnt(4) (retires prev-tile A1' -> A1 readable),
//             end-ph2 vmcnt(2) (retires A0',B' -> next ph1 readable).
// K folded for q precision: q-tiles (bn<1152) NT=32, A base switches to Alo
// at t=16, B col-group repeats (kt & 15).  k/v-tiles NT=16.
// 864 blocks (8 XCD chunks of 108, heavy q-blocks first within chunk).
// ---------------------------------------------------------------------------
__global__ __launch_bounds__(512, 2) void gemm_qkv8p_k(
    const f16_t* __restrict__ Ahi, const f16_t* __restrict__ Alo,
    const f16_t* __restrict__ Bt, const float* __restrict__ bias,
    float* __restrict__ outF) {
  constexpr int BM = 256, BN = 128;
  constexpr int MF = 4, NF = 1;      // BM/64, BN/128
  constexpr int TILE = (BM + BN) * 64;
  __shared__ alignas(16) f16_t lds[2 * TILE];

  const int tid = threadIdx.x;
  const int lane = tid & 63;
  const int w = tid >> 6;
  const int wm = w >> 2, wn = w & 3;

  // block mapping: chunk of 108 per XCD, heavy-first within chunk
  const int lin = (int)blockIdx.x;
  const int xcd = lin & 7, idx = lin >> 3;   // idx 0..107
  int bm, bn;
  bool qmode;
  if (idx < 36) {
    const int h = xcd * 36 + idx;            // 0..287
    bm = (h / 9) * 256;
    bn = (h % 9) * 128;
    qmode = true;
  } else {
    const int l = xcd * 72 + (idx - 36);     // 0..575
    bm = (l / 18) * 256;
    bn = 1152 + (l % 18) * 128;
    qmode = false;
  }
  const int NT = qmode ? 32 : 16;

  f32x4 acc[2][2][MF][NF];
#pragma unroll
  for (int a0 = 0; a0 < 2; ++a0)
#pragma unroll
    for (int a1 = 0; a1 < 2; ++a1)
#pragma unroll
      for (int mf = 0; mf < MF; ++mf)
#pragma unroll
        for (int nf = 0; nf < NF; ++nf)
          acc[a0][a1][mf][nf] = (f32x4){0.f, 0.f, 0.f, 0.f};

  // prologue: stage tile 0 into buf0 in need-order A0, B, A1 (2+2+2 loads)
  stage_half<128>(Ahi, bm, DD, 0, lds, w, lane);                    // A0
  stage_half<128>(Bt, bn, DD, 0, lds + BM * 64, w, lane);           // B full
  stage_half<128>(Ahi, bm + 128, DD, 0, lds + 128 * 64, w, lane);   // A1
  vwait<2>();                       // A0,B landed; A1 (2) may be in flight
  __builtin_amdgcn_s_barrier();

  f16x8 aR[MF][2], bR0[NF][2], bR1[NF][2];

  for (int t = 0; t < NT; ++t) {
    const int cur = t & 1;
    f16_t* As = lds + cur * TILE;
    f16_t* Bs = As + BM * 64;
    f16_t* Asn = lds + (cur ^ 1) * TILE;
    f16_t* Bsn = Asn + BM * 64;
    const bool pre = (t + 1 < NT);
    const int tt = t + 1;
    const f16_t* An = (qmode && tt >= 16) ? Alo : Ahi;   // K-fold base
    const int ktn = (tt & 15) << 6;                      // B repeats for lo

    // ---- phase 1: top M-half x full N (16 MFMA) --------------------------
    readA<BM, BN>(As, 0, wm, lane, aR);
    readB<BM, BN>(Bs, 0, wn, lane, bR0);
    readB<BM, BN>(Bs, 1, wn, lane, bR1);
    if (pre) {
      stage_half<128>(An, bm, DD, ktn, Asn, w, lane);               // A0' (2)
      stage_half<128>(Bt, bn, DD, ktn, Bsn, w, lane);               // B'  (2)
    }
    __builtin_amdgcn_s_barrier();
    __builtin_amdgcn_s_setprio(1);
    mfma_q<MF, NF>(acc[0][0], aR, bR0);
    mfma_q<MF, NF>(acc[0][1], aR, bR1);
    __builtin_amdgcn_s_setprio(0);
    if (pre) vwait<4>(); else vwait<0>();     // prev A1' retired -> A1 ready
    __builtin_amdgcn_s_barrier();

    // ---- phase 2: bottom M-half x full N (16 MFMA, bR reused) ------------
    readA<BM, BN>(As, 1, wm, lane, aR);
    if (pre) stage_half<128>(An, bm + 128, DD, ktn, Asn + 128 * 64, w, lane);
    __builtin_amdgcn_s_barrier();
    __builtin_amdgcn_s_setprio(1);
    mfma_q<MF, NF>(acc[1][0], aR, bR0);
    mfma_q<MF, NF>(acc[1][1], aR, bR1);
    __builtin_amdgcn_s_setprio(0);
    if (pre) vwait<2>();                      // A0',B' landed for next ph1
    __builtin_amdgcn_s_barrier();
  }

  const int q4 = lane >> 4;
  const int cn = lane & 15;
#pragma unroll
  for (int mq = 0; mq < 2; ++mq)
#pragma unroll
    for (int nq = 0; nq < 2; ++nq)
#pragma unroll
      for (int mf = 0; mf < MF; ++mf)
#pragma unroll
        for (int nf = 0; nf < NF; ++nf) {
          const int gcol = bn + nq * (BN / 2) + wn * (BN / 8) + nf * 16 + cn;
          const float bv = bias[gcol];
          const int grow0 = bm + mq * (BM / 2) + wm * (BM / 4) + mf * 16 + q4 * 4;
#pragma unroll
          for (int i = 0; i < 4; ++i) {
            const size_t oidx = (size_t)(grow0 + i) * NQKV + gcol;
            outF[oidx] = acc[mq][nq][mf][nf][i] + bv;
          }
        }
}

// ---------------------------------------------------------------------------
// Inline normalize helpers reading raw bins from qkv_f rows (1728 float2).
// ---------------------------------------------------------------------------
__device__ __forceinline__ float2 unitc(float2 a) {
  float inv = 1.0f / fmaxf(sqrtf(a.x * a.x + a.y * a.y), 1e-8f);
  return make_float2(a.x * inv, a.y * inv);
}
__device__ __forceinline__ float2 bind_bin(const float2* r, int f) {
  float2 kn = unitc(r[576 + f]);
  float2 vn = unitc(r[1152 + f]);
  return cmul(kn, vn);
}

// ---------------------------------------------------------------------------
// 3-pass parallel prefix sum over S per (batch, bin), P computed inline.
// ---------------------------------------------------------------------------
__global__ __launch_bounds__(256) void scan_pass1_k(
    const float* __restrict__ qkvF, float2* __restrict__ T) {
  const int bid = blockIdx.x;
  const int sc = bid & 63;
  const int fh = (bid >> 6) & 1;
  const int b = bid >> 7;
  const int s0 = sc * SCHUNK;
  const float2* base = (const float2*)(qkvF + ((size_t)(b * SSEQ + s0)) * NQKV);
  for (int f = fh * 256 + threadIdx.x; f < FBINS; f += 512) {
    float2 acc = make_float2(0.f, 0.f);
    const float2* r = base;
    for (int i = 0; i < SCHUNK; ++i) {
      float2 pv = bind_bin(r, f);
      acc.x += pv.x; acc.y += pv.y;
      r += NQKV / 2;
    }
    T[((size_t)b * NCHUNK + sc) * FBINS + f] = acc;
  }
}

__global__ void scan_pass2_k(float2* __restrict__ T) {
  const int idx = blockIdx.x * 256 + threadIdx.x;
  if (idx >= NB * FBINS) return;
  const int b = idx / FBINS, f = idx % FBINS;
  float2 acc = make_float2(0.f, 0.f);
  for (int sc = 0; sc < NCHUNK; ++sc) {
    size_t a = ((size_t)b * NCHUNK + sc) * FBINS + f;
    float2 v = T[a];
    T[a] = acc;
    acc.x += v.x; acc.y += v.y;
  }
}

__global__ __launch_bounds__(256) void scan_pass3_k(
    const float* __restrict__ qkvF, const float2* __restrict__ T,
    float2* __restrict__ Scum) {
  const int bid = blockIdx.x;
  const int sc = bid & 63;
  const int fh = (bid >> 6) & 1;
  const int b = bid >> 7;
  const int s0 = sc * SCHUNK;
  const float2* base = (const float2*)(qkvF + ((size_t)(b * SSEQ + s0)) * NQKV);
  for (int f = fh * 256 + threadIdx.x; f < FBINS; f += 512) {
    float2 acc = T[((size_t)b * NCHUNK + sc) * FBINS + f];
    const float2* r = base;
    size_t orow = ((size_t)(b * SSEQ + s0)) * FPAD + f;
    for (int i = 0; i < SCHUNK; ++i) {
      float2 pv = bind_bin(r, f);
      acc.x += pv.x; acc.y += pv.y;
      Scum[orow] = acc;
      r += NQKV / 2;
      orow += FPAD;
    }
  }
}

// ---------------------------------------------------------------------------
// Unbind + LN2, 2 rows per 512-thread block (halves per-row barrier cost).
// Per-row: Fq = unit(q bins); M = Scum .* conj(Fq); mixed = irfft(M) via
// packed real inverse; x2 = x + mixed; h2 = LN2(x2) -> fp16.
// ---------------------------------------------------------------------------
__global__ __launch_bounds__(512) void unbind_ln2_k(
    const float2* __restrict__ Scum, const float* __restrict__ qkvF,
    const float* __restrict__ x, float* __restrict__ x2out,
    f16_t* __restrict__ h2, const float* __restrict__ g2,
    const float* __restrict__ b2) {
  __shared__ float2 tw[256];     // e^{+2pi i t/512}
  __shared__ float2 Marr[2][513];
  __shared__ float2 bufA[2][512];
  __shared__ float2 bufB[2][512];
  __shared__ float red[2][8];
  const int tid = threadIdx.x;
  const int rh = tid >> 8;       // row half 0/1
  const int lt = tid & 255;
  const int row = blockIdx.x * 2 + rh;

  if (rh == 0) {
    float ang = 6.2831853071795864769f * (float)lt * (1.0f / 512.0f);
    tw[lt] = make_float2(cosf(ang), sinf(ang));
  }
  const float2* qrow = (const float2*)(qkvF + (size_t)row * NQKV);
  for (int t = lt; t <= 512; t += 256) {
    float2 sc = Scum[(size_t)row * FPAD + t];
    float2 fq = unitc(qrow[t]);
    Marr[rh][t] = make_float2(sc.x * fq.x + sc.y * fq.y,
                              sc.y * fq.x - sc.x * fq.y);
  }
  __syncthreads();
  // build Z into bufA
#pragma unroll
  for (int rr = 0; rr < 2; ++rr) {
    int t = lt + rr * 256;
    float2 a = Marr[rh][t];
    float2 b = Marr[rh][512 - t];
    float2 E = make_float2(0.5f * (a.x + b.x), 0.5f * (a.y - b.y));
    float2 Dd = make_float2(0.5f * (a.x - b.x), 0.5f * (a.y + b.y));
    float ang = 6.2831853071795864769f * (float)t * (1.0f / 1024.0f);
    float cw = cosf(ang), sw = sinf(ang);
    float2 O = make_float2(cw * Dd.x - sw * Dd.y, cw * Dd.y + sw * Dd.x);
    bufA[rh][t] = make_float2(E.x - O.y, E.y + O.x);
  }
  __syncthreads();
  float2* res = fft512(bufA[rh], bufB[rh], tw, lt);

  const float* xr = x + (size_t)row * DD;
  float v[2][2];
  float ls = 0.f, lq = 0.f;
#pragma unroll
  for (int rr = 0; rr < 2; ++rr) {
    int n = lt + rr * 256;
    float2 z = res[n];
    float2 xv = *(const float2*)(xr + 2 * n);
    float v0 = xv.x + z.x * (1.0f / 512.0f);
    float v1 = xv.y + z.y * (1.0f / 512.0f);
    *(float2*)(x2out + (size_t)row * DD + 2 * n) = make_float2(v0, v1);
    v[rr][0] = v0; v[rr][1] = v1;
    ls += v0 + v1;
    lq += v0 * v0 + v1 * v1;
  }
#pragma unroll
  for (int o = 32; o > 0; o >>= 1) {
    ls += __shfl_down(ls, o);
    lq += __shfl_down(lq, o);
  }
  const int lane = tid & 63, w4 = (tid >> 6) & 3;
  if (lane == 0) { red[rh][w4] = ls; red[rh][w4 + 4] = lq; }
  __syncthreads();
  const float S = red[rh][0] + red[rh][1] + red[rh][2] + red[rh][3];
  const float Q = red[rh][4] + red[rh][5] + red[rh][6] + red[rh][7];
  const float mean = S * (1.f / 1024.f);
  const float var = Q * (1.f / 1024.f) - mean * mean;
  const float rs = rsqrtf(var + 1e-5f);
  f16_t* hr = h2 + (size_t)row * DD;
#pragma unroll
  for (int rr = 0; rr < 2; ++rr) {
    int n = lt + rr * 256;
    float2 gv = *(const float2*)(g2 + 2 * n);
    float2 bv = *(const float2*)(b2 + 2 * n);
    f16x2 hp;
    hp[0] = (f16_t)((v[rr][0] - mean) * rs * gv.x + bv.x);
    hp[1] = (f16_t)((v[rr][1] - mean) * rs * gv.y + bv.y);
    *(f16x2*)(hr + 2 * n) = hp;
  }
}

// ---------------------------------------------------------------------------
extern "C" void kernel_launch(void* const* d_in, const int* in_sizes, int n_in,
                              void* d_out, int out_size, void* d_ws,
                              size_t ws_size, hipStream_t stream) {
  const float* x     = (const float*)d_in[0];
  const float* Wq    = (const float*)d_in[1];
  const float* bq    = (const float*)d_in[2];
  const float* Wk    = (const float*)d_in[3];
  const float* bk    = (const float*)d_in[4];
  const float* Wv    = (const float*)d_in[5];
  const float* bv    = (const float*)d_in[6];
  const float* ln1_g = (const float*)d_in[7];
  const float* ln1_b = (const float*)d_in[8];
  const float* ln2_g = (const float*)d_in[9];
  const float* ln2_b = (const float*)d_in[10];
  const float* W1    = (const float*)d_in[11];
  const float* b1    = (const float*)d_in[12];
  const float* W2    = (const float*)d_in[13];
  const float* b2    = (const float*)d_in[14];
  float* out = (float*)d_out;

  char* p = (char*)d_ws;
  auto take = [&](size_t bytes) {
    char* r = p;
    p += (bytes + 255) & ~(size_t)255;
    return r;
  };
  f16_t* BtH   = (f16_t*)take((size_t)NQKV * DD * sizeof(f16_t));
  f16_t* W1T   = (f16_t*)take((size_t)NHID * DD * sizeof(f16_t));
  f16_t* W2T   = (f16_t*)take((size_t)DD * NHID * sizeof(f16_t));
  float* biasC = (float*)take((size_t)NQKV * sizeof(float));
  f16_t* hbuf  = (f16_t*)take((size_t)MROWS * DD * sizeof(f16_t));   // h_hi, then h2
  char*  big   = take((size_t)MROWS * NQKV * sizeof(float));         // WfAll, qkvF, mlp1
  float2* Scum = (float2*)take((size_t)MROWS * FPAD * sizeof(float2));
  float* x2    = (float*)take((size_t)MROWS * DD * sizeof(float));
  float2* Tch  = (float2*)take((size_t)NB * NCHUNK * FBINS * sizeof(float2));
  // time-disjoint aliases:
  float* WfAll   = (float*)big;
  float* qkv_f   = (float*)big;
  f16_t* mlp1    = (f16_t*)big;
  f16_t* hlo     = (f16_t*)x2;

  // 1. FFT weight rows (fp32) -> WfAll[p][k][1152]   [2 rows/block]
  wfft_k<<<3 * DD / 2, 512, 0, stream>>>(Wq, Wk, Wv, WfAll);
  // 2. transpose + cast -> BtH (3456 x 1024)
  for (int pp = 0; pp < 3; ++pp)
    transpose_cast_k<<<dim3(WFP / 32, DD / 32), 256, 0, stream>>>(
        WfAll + (size_t)pp * DD * WFP,
        BtH + (size_t)pp * WFP * DD, DD, WFP);
  // 3. FFT biases -> biasC
  bfft_k<<<3, 256, 0, stream>>>(bq, bk, bv, biasC);
  // 4. MLP weights -> transposed fp16
  transpose_cast_k<<<dim3(128, 32), 256, 0, stream>>>(W1, W1T, DD, NHID);
  transpose_cast_k<<<dim3(32, 128), 256, 0, stream>>>(W2, W2T, NHID, DD);

  // 5. h = LN1(x) -> hi/lo fp16 pair
  ln_cast2_k<<<MROWS, 256, 0, stream>>>(x, ln1_g, ln1_b, hbuf, hlo);

  // 6. Fourier bins: qkv_f = h @ rfft_rows(W)^T + rfft(bias)  [2 fat phases]
  gemm_qkv8p_k<<<864, 512, 0, stream>>>(hbuf, hlo, BtH, biasC, qkv_f);

  // 7. causal prefix sum over S
  scan_pass1_k<<<NB * NCHUNK * 2, 256, 0, stream>>>(qkv_f, Tch);
  scan_pass2_k<<<(NB * FBINS + 255) / 256, 256, 0, stream>>>(Tch);
  scan_pass3_k<<<NB * NCHUNK * 2, 256, 0, stream>>>(qkv_f, Tch, Scum);

  // 8. unbind (packed real iFFT) + residual + LN2   [2 rows/block]
  unbind_ln2_k<<<MROWS / 2, 512, 0, stream>>>(Scum, qkv_f, x, x2, hbuf,
                                              ln2_g, ln2_b);

  // 9. mlp1 = gelu(h2 @ W1 + b1)   [8-phase 256x256, 512 blocks]
  gemm8p_k<256, 256, MROWS, NHID, DD, 1><<<512, 512, 0, stream>>>(
      hbuf, W1T, b1, nullptr, nullptr, mlp1);

  // 10. out = x2 + mlp1 @ W2 + b2  [8-phase 128x256, 256 blocks = 1/CU]
  gemm8p_k<128, 256, MROWS, DD, NHID, 2><<<256, 512, 0, stream>>>(
      mlp1, W2T, b2, x2, out, nullptr);
}

// Round 4
// 475.979 us; speedup vs baseline: 1.0931x; 1.0886x over previous
//
#include <hip/hip_runtime.h>
#include <cstdint>
#include <cstddef>

// Problem constants (B=4, S=2048, D=1024)
#define DD 1024
#define SSEQ 2048
#define NB 4
#define MROWS 8192          // B*S
#define FBINS 513           // rfft bins for N=1024
#define FPAD 520            // padded row stride for Scum buffer
#define WFP 1152            // per-projection padded fp32 column count (9 tiles)
#define NQKV 3456           // 3 * WFP = 27 tiles of 128
#define NHID 4096
#define NCHUNK 64           // scan chunks over S
#define SCHUNK 32           // S per chunk

typedef _Float16 f16_t;
typedef _Float16 f16x8 __attribute__((ext_vector_type(8)));
typedef _Float16 f16x2 __attribute__((ext_vector_type(2)));
typedef float f32x4 __attribute__((ext_vector_type(4)));

__device__ __forceinline__ float2 cmul(float2 a, float2 b) {
  return make_float2(a.x * b.x - a.y * b.y, a.x * b.y + a.y * b.x);
}

// Async global->LDS 16B copy (m97: width=16 emits global_load_lds_dwordx4).
__device__ __forceinline__ void async_cp16(const void* g, void* l) {
  __builtin_amdgcn_global_load_lds(
      (const __attribute__((address_space(1))) void*)g,
      (__attribute__((address_space(3))) void*)l, 16, 0, 0);
}

// Counted vmcnt waits (T4): literal immediates via specialization.
template <int N> __device__ __forceinline__ void vwait();
template <> __device__ __forceinline__ void vwait<0>() { asm volatile("s_waitcnt vmcnt(0)" ::: "memory"); }
template <> __device__ __forceinline__ void vwait<1>() { asm volatile("s_waitcnt vmcnt(1)" ::: "memory"); }
template <> __device__ __forceinline__ void vwait<2>() { asm volatile("s_waitcnt vmcnt(2)" ::: "memory"); }
template <> __device__ __forceinline__ void vwait<3>() { asm volatile("s_waitcnt vmcnt(3)" ::: "memory"); }
template <> __device__ __forceinline__ void vwait<4>() { asm volatile("s_waitcnt vmcnt(4)" ::: "memory"); }

// Branchless erf-based gelu, A&S 7.1.26 (|eps_erf| <= 1.5e-7).
__device__ __forceinline__ float fast_gelu(float val) {
  float av = __builtin_fabsf(val);
  float z = av * 0.70710678118654752f;
  float t = __builtin_amdgcn_rcpf(__builtin_fmaf(0.3275911f, z, 1.0f));
  float poly = t * __builtin_fmaf(t,
      __builtin_fmaf(t, __builtin_fmaf(t,
          __builtin_fmaf(t, 1.061405429f, -1.453152027f),
          1.421413741f), -0.284496736f), 0.254829592f);
  float e = __builtin_amdgcn_exp2f(z * z * -1.4426950408889634f);
  float w = poly * e;
  float r = fmaxf(val, 0.0f);
  return __builtin_fmaf(-0.5f * av, w, r);
}

// 1024-pt complex FFT over LDS ping-pong buffers; result lands back in bufA.
// lt in [0,256).  __syncthreads syncs the whole block (all rows in lockstep).
__device__ __forceinline__ void fft1024(float2* bufA, float2* bufB,
                                        const float2* tw, int lt) {
  float2* s = bufA;
  float2* d = bufB;
  for (int m = 1; m < 1024; m <<= 1) {
#pragma unroll
    for (int r2 = 0; r2 < 2; ++r2) {
      int u = lt + r2 * 256;
      int k = u & (m - 1);
      int jm = u - k;
      float2 c0 = s[u];
      float2 c1 = s[u + 512];
      float2 wt = tw[jm];
      float2 su = make_float2(c0.x + c1.x, c0.y + c1.y);
      float2 df = make_float2(c0.x - c1.x, c0.y - c1.y);
      float2 pr = cmul(wt, df);
      d[2 * jm + k] = su;
      d[2 * jm + k + m] = pr;
    }
    __syncthreads();
    float2* tmp = s; s = d; d = tmp;
  }
}

// 512-pt complex FFT (one butterfly per thread per stage); returns result ptr.
__device__ __forceinline__ float2* fft512(float2* bufA, float2* bufB,
                                          const float2* tw, int lt) {
  float2* s = bufA;
  float2* d = bufB;
  for (int m = 1; m < 512; m <<= 1) {
    int u = lt;
    int k = u & (m - 1);
    int jm = u - k;
    float2 c0 = s[u];
    float2 c1 = s[u + 256];
    float2 wt = tw[jm];
    float2 su = make_float2(c0.x + c1.x, c0.y + c1.y);
    float2 df = make_float2(c0.x - c1.x, c0.y - c1.y);
    float2 pr = cmul(wt, df);
    d[2 * jm + k] = su;
    d[2 * jm + k + m] = pr;
    __syncthreads();
    float2* tmp = s; s = d; d = tmp;
  }
  return s;   // 9 stages -> result in bufB
}

// ---------------------------------------------------------------------------
// Weight-row FFT, 2 rows per 512-thread block (halves per-row barrier cost).
// WfAll[p][k][j] = interleaved Re/Im of rfft(W_p[k, :]).
// ---------------------------------------------------------------------------
__global__ __launch_bounds__(512) void wfft_k(
    const float* __restrict__ Wq, const float* __restrict__ Wk,
    const float* __restrict__ Wv, float* __restrict__ WfAll) {
  __shared__ float2 tw[512];
  __shared__ float2 bufA[2][1024];
  __shared__ float2 bufB[2][1024];
  const int tid = threadIdx.x;
  const int rh = tid >> 8;          // row half 0/1
  const int lt = tid & 255;
  const int row = blockIdx.x * 2 + rh;
  const int p = row >> 10, k = row & 1023;
  const float* W = (p == 0) ? Wq : ((p == 1) ? Wk : Wv);
  if (rh == 0) {
    for (int t = lt; t < 512; t += 256) {
      float ang = -6.2831853071795864769f * (float)t * (1.0f / 1024.0f);
      tw[t] = make_float2(cosf(ang), sinf(ang));
    }
  }
  const float* src = W + (size_t)k * DD;
  for (int t = lt; t < 1024; t += 256) bufA[rh][t] = make_float2(src[t], 0.f);
  __syncthreads();
  fft1024(bufA[rh], bufB[rh], tw, lt);
  float* dst = WfAll + ((size_t)p * DD + k) * WFP;
  for (int t = lt; t <= 512; t += 256) {
    float2 f = bufA[rh][t];
    dst[2 * t] = f.x;
    dst[2 * t + 1] = f.y;
  }
  for (int j = 1026 + lt; j < WFP; j += 256) dst[j] = 0.f;
}

// ---------------------------------------------------------------------------
// Bias FFT (blocks 0..2).
// ---------------------------------------------------------------------------
__global__ __launch_bounds__(256) void bfft_k(
    const float* __restrict__ bq, const float* __restrict__ bk,
    const float* __restrict__ bv, float* __restrict__ biasC) {
  __shared__ float2 tw[512];
  __shared__ float2 bufA[1024];
  __shared__ float2 bufB[1024];
  const int tid = threadIdx.x;
  const int p = blockIdx.x;
  const float* bsrc = (p == 0) ? bq : ((p == 1) ? bk : bv);
  for (int t = tid; t < 512; t += 256) {
    float ang = -6.2831853071795864769f * (float)t * (1.0f / 1024.0f);
    tw[t] = make_float2(cosf(ang), sinf(ang));
  }
  for (int t = tid; t < 1024; t += 256) bufA[t] = make_float2(bsrc[t], 0.f);
  __syncthreads();
  fft1024(bufA, bufB, tw, tid);
  float* dst = biasC + (size_t)p * WFP;
  for (int t = tid; t <= 512; t += 256) {
    float2 f = bufA[t];
    dst[2 * t] = f.x;
    dst[2 * t + 1] = f.y;
  }
  for (int j = 1026 + tid; j < WFP; j += 256) dst[j] = 0.f;
}

// ---------------------------------------------------------------------------
// Transpose + cast fp32 (K x N) -> fp16 (N x K)
// ---------------------------------------------------------------------------
__global__ __launch_bounds__(256) void transpose_cast_k(
    const float* __restrict__ W, f16_t* __restrict__ Wt, int K, int N) {
  __shared__ float tile[32][33];
  const int tx = threadIdx.x & 31, ty = threadIdx.x >> 5;  // 32 x 8
  const int n0 = blockIdx.x * 32, k0 = blockIdx.y * 32;
#pragma unroll
  for (int i = 0; i < 32; i += 8)
    tile[ty + i][tx] = W[(size_t)(k0 + ty + i) * N + n0 + tx];
  __syncthreads();
#pragma unroll
  for (int i = 0; i < 32; i += 8)
    Wt[(size_t)(n0 + ty + i) * K + k0 + tx] = (f16_t)tile[tx][ty + i];
}

// ---------------------------------------------------------------------------
// LayerNorm (fp32 in) -> fp16.  One block per row of 1024.
// (q-lo path removed: all three projections now single-fp16, like k/v were.)
// ---------------------------------------------------------------------------
__global__ __launch_bounds__(256) void ln_cast_k(
    const float* __restrict__ x, const float* __restrict__ g,
    const float* __restrict__ b, f16_t* __restrict__ hH) {
  const int row = blockIdx.x, tid = threadIdx.x;
  __shared__ float red[8];
  const float* xr = x + (size_t)row * DD;
  float v[4], ls = 0.f, lq = 0.f;
#pragma unroll
  for (int i = 0; i < 4; ++i) {
    v[i] = xr[i * 256 + tid];
    ls += v[i];
    lq += v[i] * v[i];
  }
#pragma unroll
  for (int o = 32; o > 0; o >>= 1) {
    ls += __shfl_down(ls, o);
    lq += __shfl_down(lq, o);
  }
  const int lane = tid & 63, w = tid >> 6;
  if (lane == 0) { red[w] = ls; red[w + 4] = lq; }
  __syncthreads();
  const float S = red[0] + red[1] + red[2] + red[3];
  const float Q = red[4] + red[5] + red[6] + red[7];
  const float mean = S * (1.f / 1024.f);
  const float var = Q * (1.f / 1024.f) - mean * mean;
  const float rs = rsqrtf(var + 1e-5f);
#pragma unroll
  for (int i = 0; i < 4; ++i) {
    int n = i * 256 + tid;
    float val = (v[i] - mean) * rs * g[n] + b[n];
    hH[(size_t)row * DD + n] = (f16_t)val;
  }
}

// ---------------------------------------------------------------------------
// QKV GEMM, uniform fp16: M=8192, N=3456, K=1024.  128x128 tile, 32 KB LDS,
// proven m97-style staging loop (R1 structure), XCD snake, 1728 blocks.
// launch_bounds(256,3): ~136 unified regs fit 3 waves/EU -> 3 blocks/CU
// (12 waves/CU, up from R1's 8) for better implicit wave overlap.
// ---------------------------------------------------------------------------
__global__ __launch_bounds__(256, 3) void gemm_qkv_k(
    const f16_t* __restrict__ A, const f16_t* __restrict__ Bt,
    const float* __restrict__ bias, float* __restrict__ outF) {
  __shared__ alignas(16) f16_t AsH[128 * 64];
  __shared__ alignas(16) f16_t BsH[128 * 64];
  const int tid = threadIdx.x;
  const int lane = tid & 63;
  const int w = tid >> 6;
  const int wm = w >> 1, wn = w & 1;

  const int lin = blockIdx.x;
  const int s = (lin & 7) * 216 + (lin >> 3);
  const int g = s / 108;
  const int r = s % 108;
  const int n = r >> 2;
  const int m0 = g * 4 + (r & 3);
  const int bn = n * 128;
  const int bm = m0 * 128;

  f32x4 acc[4][4];
#pragma unroll
  for (int i = 0; i < 4; ++i)
#pragma unroll
    for (int j = 0; j < 4; ++j) acc[i][j] = (f32x4){0.f, 0.f, 0.f, 0.f};

  const int srow = lane >> 3;
  const int slot = lane & 7;

  for (int kt = 0; kt < 1024; kt += 64) {
#pragma unroll
    for (int i = 0; i < 4; ++i) {
      const int rb = (i * 4 + w) * 8;
      const int row = rb + srow;
      const int gg = (slot - (row & 7)) & 7;
      size_t ga = (size_t)(bm + row) * 1024 + kt + gg * 8;
      size_t gb = (size_t)(bn + row) * 1024 + kt + gg * 8;
      async_cp16(A + ga, &AsH[rb * 64]);
      async_cp16(Bt + gb, &BsH[rb * 64]);
    }
    __syncthreads();
#pragma unroll
    for (int ks = 0; ks < 2; ++ks) {
      const int cgbase = ks * 4 + (lane >> 4);
      f16x8 ah[4], bh[4];
#pragma unroll
      for (int mt = 0; mt < 4; ++mt) {
        int m = wm * 64 + mt * 16 + (lane & 15);
        int sl = (cgbase + (m & 7)) & 7;
        ah[mt] = *(const f16x8*)(&AsH[m * 64 + sl * 8]);
      }
#pragma unroll
      for (int nt = 0; nt < 4; ++nt) {
        int nn = wn * 64 + nt * 16 + (lane & 15);
        int sl = (cgbase + (nn & 7)) & 7;
        bh[nt] = *(const f16x8*)(&BsH[nn * 64 + sl * 8]);
      }
#pragma unroll
      for (int mt = 0; mt < 4; ++mt)
#pragma unroll
        for (int nt = 0; nt < 4; ++nt)
          acc[mt][nt] = __builtin_amdgcn_mfma_f32_16x16x32_f16(
              ah[mt], bh[nt], acc[mt][nt], 0, 0, 0);
    }
    __syncthreads();
  }

  const int q = lane >> 4;
  const int cn = lane & 15;
#pragma unroll
  for (int mt = 0; mt < 4; ++mt) {
#pragma unroll
    for (int nt = 0; nt < 4; ++nt) {
      const int gcol = bn + wn * 64 + nt * 16 + cn;
      const float bv = bias[gcol];
      const int grow0 = bm + wm * 64 + mt * 16 + q * 4;
#pragma unroll
      for (int i = 0; i < 4; ++i) {
        size_t idx = (size_t)(grow0 + i) * NQKV + gcol;
        outF[idx] = acc[mt][nt][i] + bv;
      }
    }
  }
}

// ---------------------------------------------------------------------------
// 8-phase GEMM building blocks (strip-interleaved wave decomposition).
// ---------------------------------------------------------------------------
template <int RHALF>
__device__ __forceinline__ void stage_half(const f16_t* __restrict__ G,
                                           int grow0, int ldk, int kt,
                                           f16_t* ls, int w, int lane) {
  const int srow = lane >> 3;
  const int slot = lane & 7;
#pragma unroll
  for (int j = 0; j < RHALF / 64; ++j) {
    const int rb = (w + j * 8) * 8;           // row block within half
    const int row = rb + srow;
    const int gg = (slot - (row & 7)) & 7;    // pre-swizzled global col-group
    async_cp16(G + (size_t)(grow0 + row) * ldk + kt + gg * 8, ls + rb * 64);
  }
}

template <int BM, int BN>
__device__ __forceinline__ void readA(const f16_t* As, int mq, int wm, int lane,
                                      f16x8 (&aR)[BM / 64][2]) {
#pragma unroll
  for (int mf = 0; mf < BM / 64; ++mf) {
    const int m = mq * (BM / 2) + wm * (BM / 4) + mf * 16 + (lane & 15);
#pragma unroll
    for (int ks = 0; ks < 2; ++ks) {
      const int cg = ks * 4 + (lane >> 4);
      const int sl = (cg + (m & 7)) & 7;
      aR[mf][ks] = *(const f16x8*)(As + m * 64 + sl * 8);
    }
  }
}

template <int BM, int BN>
__device__ __forceinline__ void readB(const f16_t* Bs, int nq, int wn, int lane,
                                      f16x8 (&bR)[BN / 128][2]) {
#pragma unroll
  for (int nf = 0; nf < BN / 128; ++nf) {
    const int n = nq * (BN / 2) + wn * (BN / 8) + nf * 16 + (lane & 15);
#pragma unroll
    for (int ks = 0; ks < 2; ++ks) {
      const int cg = ks * 4 + (lane >> 4);
      const int sl = (cg + (n & 7)) & 7;
      bR[nf][ks] = *(const f16x8*)(Bs + n * 64 + sl * 8);
    }
  }
}

template <int MF, int NF>
__device__ __forceinline__ void mfma_q(f32x4 (&acc)[MF][NF],
                                       const f16x8 (&aR)[MF][2],
                                       const f16x8 (&bR)[NF][2]) {
#pragma unroll
  for (int ks = 0; ks < 2; ++ks)
#pragma unroll
    for (int mf = 0; mf < MF; ++mf)
#pragma unroll
      for (int nf = 0; nf < NF; ++nf)
        acc[mf][nf] = __builtin_amdgcn_mfma_f32_16x16x32_f16(
            aR[mf][ks], bR[nf][ks], acc[mf][nf], 0, 0, 0);
}

// EPI 1: fast-gelu -> fp16.  EPI 2: +bias+resid -> fp32.
template <int BM, int BN, int MM, int NN, int KK, int EPI>
__global__ __launch_bounds__(512, 2) void gemm8p_k(
    const f16_t* __restrict__ A, const f16_t* __restrict__ Bt,
    const float* __restrict__ bias, const float* __restrict__ resid,
    float* __restrict__ outF, f16_t* __restrict__ outH) {
  constexpr int MF = BM / 64;      // M-frags per phase (one strip)
  constexpr int NF = BN / 128;     // N-frags per phase
  constexpr int LA = BM / 128;     // loads/thread per A-half
  constexpr int LB = BN / 128;     // loads/thread per B-half
  constexpr int NT = KK / 64;
  constexpr int TILE = (BM + BN) * 64;
  __shared__ alignas(16) f16_t lds[2 * TILE];

  const int tid = threadIdx.x;
  const int lane = tid & 63;
  const int w = tid >> 6;          // 8 waves
  const int wm = w >> 2;           // 0..1
  const int wn = w & 3;            // 0..3

  constexpr int ntm = MM / BM, ntn = NN / BN;
  constexpr int per = (ntm * ntn) / 8;   // nwg % 8 == 0 for both instantiations
  const int lin = (int)blockIdx.x;
  const int s = (lin & 7) * per + (lin >> 3);
  const int bn = (s % ntn) * BN;
  const int bm = (s / ntn) * BM;

  f32x4 acc[2][2][MF][NF];
#pragma unroll
  for (int a0 = 0; a0 < 2; ++a0)
#pragma unroll
    for (int a1 = 0; a1 < 2; ++a1)
#pragma unroll
      for (int mf = 0; mf < MF; ++mf)
#pragma unroll
        for (int nf = 0; nf < NF; ++nf)
          acc[a0][a1][mf][nf] = (f32x4){0.f, 0.f, 0.f, 0.f};

  // prologue: stage tile 0 in need-order A0,B0,B1,A1; wait for A0,B0.
  {
    f16_t* A0s = lds;
    f16_t* B0s = lds + BM * 64;
    stage_half<BM / 2>(A, bm, KK, 0, A0s, w, lane);
    stage_half<BN / 2>(Bt, bn, KK, 0, B0s, w, lane);
    stage_half<BN / 2>(Bt, bn + BN / 2, KK, 0, B0s + (BN / 2) * 64, w, lane);
    stage_half<BM / 2>(A, bm + BM / 2, KK, 0, A0s + (BM / 2) * 64, w, lane);
  }
  vwait<LA + LB>();
  __builtin_amdgcn_s_barrier();

  f16x8 aR[MF][2], bR0[NF][2], bR1[NF][2];

  for (int t = 0; t < NT; ++t) {
    const int cur = t & 1;
    f16_t* As = lds + cur * TILE;
    f16_t* Bs = As + BM * 64;
    f16_t* Asn = lds + (cur ^ 1) * TILE;
    f16_t* Bsn = Asn + BM * 64;
    const bool pre = (t + 1 < NT);
    const int ktn = (t + 1) << 6;

    // ---- phase 1: Q(0,0) --------------------------------------------------
    readA<BM, BN>(As, 0, wm, lane, aR);
    readB<BM, BN>(Bs, 0, wn, lane, bR0);
    if (pre) stage_half<BM / 2>(A, bm, KK, ktn, Asn, w, lane);
    __builtin_amdgcn_s_barrier();
    __builtin_amdgcn_s_setprio(1);
    mfma_q<MF, NF>(acc[0][0], aR, bR0);
    __builtin_amdgcn_s_setprio(0);
    if (pre) vwait<2 * LA>(); else vwait<LA>();
    __builtin_amdgcn_s_barrier();

    // ---- phase 2: Q(0,1) --------------------------------------------------
    readB<BM, BN>(Bs, 1, wn, lane, bR1);
    if (pre) stage_half<BN / 2>(Bt, bn, KK, ktn, Bsn, w, lane);
    __builtin_amdgcn_s_barrier();
    __builtin_amdgcn_s_setprio(1);
    mfma_q<MF, NF>(acc[0][1], aR, bR1);
    __builtin_amdgcn_s_setprio(0);
    if (pre) vwait<LA + LB>(); else vwait<0>();
    __builtin_amdgcn_s_barrier();

    // ---- phase 3: Q(1,0) --------------------------------------------------
    readA<BM, BN>(As, 1, wm, lane, aR);
    if (pre) stage_half<BN / 2>(Bt, bn + BN / 2, KK, ktn,
                                Bsn + (BN / 2) * 64, w, lane);
    __builtin_amdgcn_s_barrier();
    __builtin_amdgcn_s_setprio(1);
    mfma_q<MF, NF>(acc[1][0], aR, bR0);
    __builtin_amdgcn_s_setprio(0);
    __builtin_amdgcn_s_barrier();              // no vmcnt (ph4 reads nothing)

    // ---- phase 4: Q(1,1) --------------------------------------------------
    if (pre) stage_half<BM / 2>(A, bm + BM / 2, KK, ktn,
                                Asn + (BM / 2) * 64, w, lane);
    __builtin_amdgcn_s_barrier();
    __builtin_amdgcn_s_setprio(1);
    mfma_q<MF, NF>(acc[1][1], aR, bR1);
    __builtin_amdgcn_s_setprio(0);
    if (pre) vwait<LA + LB>();                 // boundary: A0',B0' landed
    __builtin_amdgcn_s_barrier();
  }

  const int q4 = lane >> 4;
  const int cn = lane & 15;
#pragma unroll
  for (int mq = 0; mq < 2; ++mq)
#pragma unroll
    for (int nq = 0; nq < 2; ++nq)
#pragma unroll
      for (int mf = 0; mf < MF; ++mf)
#pragma unroll
        for (int nf = 0; nf < NF; ++nf) {
          const int gcol = bn + nq * (BN / 2) + wn * (BN / 8) + nf * 16 + cn;
          const float bv = bias[gcol];
          const int grow0 = bm + mq * (BM / 2) + wm * (BM / 4) + mf * 16 + q4 * 4;
#pragma unroll
          for (int i = 0; i < 4; ++i) {
            const float val = acc[mq][nq][mf][nf][i] + bv;
            const size_t idx = (size_t)(grow0 + i) * NN + gcol;
            if (EPI == 1) {
              outH[idx] = (f16_t)fast_gelu(val);
            } else {
              outF[idx] = val + resid[idx];
            }
          }
        }
}

// ---------------------------------------------------------------------------
// Inline normalize helpers reading raw bins from qkv_f rows (1728 float2).
// ---------------------------------------------------------------------------
__device__ __forceinline__ float2 unitc(float2 a) {
  float inv = 1.0f / fmaxf(sqrtf(a.x * a.x + a.y * a.y), 1e-8f);
  return make_float2(a.x * inv, a.y * inv);
}
__device__ __forceinline__ float2 bind_bin(const float2* r, int f) {
  float2 kn = unitc(r[576 + f]);
  float2 vn = unitc(r[1152 + f]);
  return cmul(kn, vn);
}

// ---------------------------------------------------------------------------
// 3-pass parallel prefix sum over S per (batch, bin), P computed inline.
// ---------------------------------------------------------------------------
__global__ __launch_bounds__(256) void scan_pass1_k(
    const float* __restrict__ qkvF, float2* __restrict__ T) {
  const int bid = blockIdx.x;
  const int sc = bid & 63;
  const int fh = (bid >> 6) & 1;
  const int b = bid >> 7;
  const int s0 = sc * SCHUNK;
  const float2* base = (const float2*)(qkvF + ((size_t)(b * SSEQ + s0)) * NQKV);
  for (int f = fh * 256 + threadIdx.x; f < FBINS; f += 512) {
    float2 acc = make_float2(0.f, 0.f);
    const float2* r = base;
    for (int i = 0; i < SCHUNK; ++i) {
      float2 pv = bind_bin(r, f);
      acc.x += pv.x; acc.y += pv.y;
      r += NQKV / 2;
    }
    T[((size_t)b * NCHUNK + sc) * FBINS + f] = acc;
  }
}

__global__ void scan_pass2_k(float2* __restrict__ T) {
  const int idx = blockIdx.x * 256 + threadIdx.x;
  if (idx >= NB * FBINS) return;
  const int b = idx / FBINS, f = idx % FBINS;
  float2 acc = make_float2(0.f, 0.f);
  for (int sc = 0; sc < NCHUNK; ++sc) {
    size_t a = ((size_t)b * NCHUNK + sc) * FBINS + f;
    float2 v = T[a];
    T[a] = acc;
    acc.x += v.x; acc.y += v.y;
  }
}

__global__ __launch_bounds__(256) void scan_pass3_k(
    const float* __restrict__ qkvF, const float2* __restrict__ T,
    float2* __restrict__ Scum) {
  const int bid = blockIdx.x;
  const int sc = bid & 63;
  const int fh = (bid >> 6) & 1;
  const int b = bid >> 7;
  const int s0 = sc * SCHUNK;
  const float2* base = (const float2*)(qkvF + ((size_t)(b * SSEQ + s0)) * NQKV);
  for (int f = fh * 256 + threadIdx.x; f < FBINS; f += 512) {
    float2 acc = T[((size_t)b * NCHUNK + sc) * FBINS + f];
    const float2* r = base;
    size_t orow = ((size_t)(b * SSEQ + s0)) * FPAD + f;
    for (int i = 0; i < SCHUNK; ++i) {
      float2 pv = bind_bin(r, f);
      acc.x += pv.x; acc.y += pv.y;
      Scum[orow] = acc;
      r += NQKV / 2;
      orow += FPAD;
    }
  }
}

// ---------------------------------------------------------------------------
// Unbind + LN2, 2 rows per 512-thread block (halves per-row barrier cost).
// Per-row: Fq = unit(q bins); M = Scum .* conj(Fq); mixed = irfft(M) via
// packed real inverse; x2 = x + mixed; h2 = LN2(x2) -> fp16.
// ---------------------------------------------------------------------------
__global__ __launch_bounds__(512) void unbind_ln2_k(
    const float2* __restrict__ Scum, const float* __restrict__ qkvF,
    const float* __restrict__ x, float* __restrict__ x2out,
    f16_t* __restrict__ h2, const float* __restrict__ g2,
    const float* __restrict__ b2) {
  __shared__ float2 tw[256];     // e^{+2pi i t/512}
  __shared__ float2 Marr[2][513];
  __shared__ float2 bufA[2][512];
  __shared__ float2 bufB[2][512];
  __shared__ float red[2][8];
  const int tid = threadIdx.x;
  const int rh = tid >> 8;       // row half 0/1
  const int lt = tid & 255;
  const int row = blockIdx.x * 2 + rh;

  if (rh == 0) {
    float ang = 6.2831853071795864769f * (float)lt * (1.0f / 512.0f);
    tw[lt] = make_float2(cosf(ang), sinf(ang));
  }
  const float2* qrow = (const float2*)(qkvF + (size_t)row * NQKV);
  for (int t = lt; t <= 512; t += 256) {
    float2 sc = Scum[(size_t)row * FPAD + t];
    float2 fq = unitc(qrow[t]);
    Marr[rh][t] = make_float2(sc.x * fq.x + sc.y * fq.y,
                              sc.y * fq.x - sc.x * fq.y);
  }
  __syncthreads();
  // build Z into bufA
#pragma unroll
  for (int rr = 0; rr < 2; ++rr) {
    int t = lt + rr * 256;
    float2 a = Marr[rh][t];
    float2 b = Marr[rh][512 - t];
    float2 E = make_float2(0.5f * (a.x + b.x), 0.5f * (a.y - b.y));
    float2 Dd = make_float2(0.5f * (a.x - b.x), 0.5f * (a.y + b.y));
    float ang = 6.2831853071795864769f * (float)t * (1.0f / 1024.0f);
    float cw = cosf(ang), sw = sinf(ang);
    float2 O = make_float2(cw * Dd.x - sw * Dd.y, cw * Dd.y + sw * Dd.x);
    bufA[rh][t] = make_float2(E.x - O.y, E.y + O.x);
  }
  __syncthreads();
  float2* res = fft512(bufA[rh], bufB[rh], tw, lt);

  const float* xr = x + (size_t)row * DD;
  float v[2][2];
  float ls = 0.f, lq = 0.f;
#pragma unroll
  for (int rr = 0; rr < 2; ++rr) {
    int n = lt + rr * 256;
    float2 z = res[n];
    float2 xv = *(const float2*)(xr + 2 * n);
    float v0 = xv.x + z.x * (1.0f / 512.0f);
    float v1 = xv.y + z.y * (1.0f / 512.0f);
    *(float2*)(x2out + (size_t)row * DD + 2 * n) = make_float2(v0, v1);
    v[rr][0] = v0; v[rr][1] = v1;
    ls += v0 + v1;
    lq += v0 * v0 + v1 * v1;
  }
#pragma unroll
  for (int o = 32; o > 0; o >>= 1) {
    ls += __shfl_down(ls, o);
    lq += __shfl_down(lq, o);
  }
  const int lane = tid & 63, w4 = (tid >> 6) & 3;
  if (lane == 0) { red[rh][w4] = ls; red[rh][w4 + 4] = lq; }
  __syncthreads();
  const float S = red[rh][0] + red[rh][1] + red[rh][2] + red[rh][3];
  const float Q = red[rh][4] + red[rh][5] + red[rh][6] + red[rh][7];
  const float mean = S * (1.f / 1024.f);
  const float var = Q * (1.f / 1024.f) - mean * mean;
  const float rs = rsqrtf(var + 1e-5f);
  f16_t* hr = h2 + (size_t)row * DD;
#pragma unroll
  for (int rr = 0; rr < 2; ++rr) {
    int n = lt + rr * 256;
    float2 gv = *(const float2*)(g2 + 2 * n);
    float2 bv = *(const float2*)(b2 + 2 * n);
    f16x2 hp;
    hp[0] = (f16_t)((v[rr][0] - mean) * rs * gv.x + bv.x);
    hp[1] = (f16_t)((v[rr][1] - mean) * rs * gv.y + bv.y);
    *(f16x2*)(hr + 2 * n) = hp;
  }
}

// ---------------------------------------------------------------------------
extern "C" void kernel_launch(void* const* d_in, const int* in_sizes, int n_in,
                              void* d_out, int out_size, void* d_ws,
                              size_t ws_size, hipStream_t stream) {
  const float* x     = (const float*)d_in[0];
  const float* Wq    = (const float*)d_in[1];
  const float* bq    = (const float*)d_in[2];
  const float* Wk    = (const float*)d_in[3];
  const float* bk    = (const float*)d_in[4];
  const float* Wv    = (const float*)d_in[5];
  const float* bv    = (const float*)d_in[6];
  const float* ln1_g = (const float*)d_in[7];
  const float* ln1_b = (const float*)d_in[8];
  const float* ln2_g = (const float*)d_in[9];
  const float* ln2_b = (const float*)d_in[10];
  const float* W1    = (const float*)d_in[11];
  const float* b1    = (const float*)d_in[12];
  const float* W2    = (const float*)d_in[13];
  const float* b2    = (const float*)d_in[14];
  float* out = (float*)d_out;

  char* p = (char*)d_ws;
  auto take = [&](size_t bytes) {
    char* r = p;
    p += (bytes + 255) & ~(size_t)255;
    return r;
  };
  f16_t* BtH   = (f16_t*)take((size_t)NQKV * DD * sizeof(f16_t));
  f16_t* W1T   = (f16_t*)take((size_t)NHID * DD * sizeof(f16_t));
  f16_t* W2T   = (f16_t*)take((size_t)DD * NHID * sizeof(f16_t));
  float* biasC = (float*)take((size_t)NQKV * sizeof(float));
  f16_t* hbuf  = (f16_t*)take((size_t)MROWS * DD * sizeof(f16_t));   // h, then h2
  char*  big   = take((size_t)MROWS * NQKV * sizeof(float));         // WfAll, qkvF, mlp1
  float2* Scum = (float2*)take((size_t)MROWS * FPAD * sizeof(float2));
  float* x2    = (float*)take((size_t)MROWS * DD * sizeof(float));
  float2* Tch  = (float2*)take((size_t)NB * NCHUNK * FBINS * sizeof(float2));
  // time-disjoint aliases:
  float* WfAll   = (float*)big;
  float* qkv_f   = (float*)big;
  f16_t* mlp1    = (f16_t*)big;

  // 1. FFT weight rows (fp32) -> WfAll[p][k][1152]   [2 rows/block]
  wfft_k<<<3 * DD / 2, 512, 0, stream>>>(Wq, Wk, Wv, WfAll);
  // 2. transpose + cast -> BtH (3456 x 1024)
  for (int pp = 0; pp < 3; ++pp)
    transpose_cast_k<<<dim3(WFP / 32, DD / 32), 256, 0, stream>>>(
        WfAll + (size_t)pp * DD * WFP,
        BtH + (size_t)pp * WFP * DD, DD, WFP);
  // 3. FFT biases -> biasC
  bfft_k<<<3, 256, 0, stream>>>(bq, bk, bv, biasC);
  // 4. MLP weights -> transposed fp16
  transpose_cast_k<<<dim3(128, 32), 256, 0, stream>>>(W1, W1T, DD, NHID);
  transpose_cast_k<<<dim3(32, 128), 256, 0, stream>>>(W2, W2T, NHID, DD);

  // 5. h = LN1(x) -> fp16
  ln_cast_k<<<MROWS, 256, 0, stream>>>(x, ln1_g, ln1_b, hbuf);

  // 6. Fourier bins: qkv_f = h @ rfft_rows(W)^T + rfft(bias)
  //    [uniform fp16 128x128, 1728 blocks, 3 blocks/CU]
  gemm_qkv_k<<<(NQKV / 128) * (MROWS / 128), 256, 0, stream>>>(
      hbuf, BtH, biasC, qkv_f);

  // 7. causal prefix sum over S
  scan_pass1_k<<<NB * NCHUNK * 2, 256, 0, stream>>>(qkv_f, Tch);
  scan_pass2_k<<<(NB * FBINS + 255) / 256, 256, 0, stream>>>(Tch);
  scan_pass3_k<<<NB * NCHUNK * 2, 256, 0, stream>>>(qkv_f, Tch, Scum);

  // 8. unbind (packed real iFFT) + residual + LN2   [2 rows/block]
  unbind_ln2_k<<<MROWS / 2, 512, 0, stream>>>(Scum, qkv_f, x, x2, hbuf,
                                              ln2_g, ln2_b);

  // 9. mlp1 = gelu(h2 @ W1 + b1)   [8-phase 256x256, 512 blocks]
  gemm8p_k<256, 256, MROWS, NHID, DD, 1><<<512, 512, 0, stream>>>(
      hbuf, W1T, b1, nullptr, nullptr, mlp1);

  // 10. out = x2 + mlp1 @ W2 + b2  [8-phase 128x256, 256 blocks = 1/CU]
  gemm8p_k<128, 256, MROWS, DD, NHID, 2><<<256, 512, 0, stream>>>(
      mlp1, W2T, b2, x2, out, nullptr);
}